// Round 13
// baseline (753.156 us; speedup 1.0000x reference)
//
#include <hip/hip_runtime.h>
#include <math.h>

#define NTT 16384
#define TS  32        // fixed forward transient length (freeze err ~1e-8 << fp32 noise)
#define KTR 32        // backward-transient tail length (closed form)
#define CHL 128       // chunk length for guarded parallel affine scans
#define GRD 192       // guard steps (rho^192 << tol)
#define NCH 128

// ---- output layout (floats) ----
static constexpr long O_MUF = 1;
static constexpr long O_VF  = O_MUF + 32L*NTT;
static constexpr long O_MUS = O_VF + 1024L*NTT;
static constexpr long O_VS  = O_MUS + 32L*NTT;
static constexpr long O_V12 = O_VS + 1024L*NTT;

// ---- workspace layout (floats) ----
static constexpr long WS_PT  = 0;              // P_t table: TS*1024
static constexpr long WS_PAR = 262144;
static constexpr int PW_VC=0, PW_PC=1024, PW_VSINF=2048, PW_V12INF=3072;
static constexpr int PW_E=4104, PW_K=6152, PW_SMU=6664;
static constexpr int PW_J=6696, PW_D=8744;
static constexpr int PW_HSVS=26152, PW_HSV12=27176, PW_SVSC=28200, PW_SV12C=29224;
static constexpr long WS_GRAM = WS_PAR + 30248;
static constexpr int  GRAM_STRIDE = 2816;
static constexpr long WS_JT = WS_GRAM;         // J_t table aliases GRAM (dead before k_gram)

// k_par1 role boundaries
static constexpr int PB_HEAD = KTR + 1;            // 33
static constexpr int PB_FILL = PB_HEAD + TS;       // 65
static constexpr int PB_MUS  = PB_FILL + 1024;     // 1089
static constexpr int PB_END  = PB_MUS + NCH;       // 1217

// LDS-only barrier: does NOT drain vmcnt -> global stores stay fire-and-forget.
__device__ __forceinline__ void lbar() {
  asm volatile("s_waitcnt lgkmcnt(0)" ::: "memory");
  __builtin_amdgcn_s_barrier();
}

// In-place 4x4 Gauss-Jordan inverse (no pivoting, SPD pivots). Static indexing only.
__device__ __forceinline__ void inv4ip(float* m) {
  #pragma unroll
  for (int p = 0; p < 4; ++p) {
    float piv = 1.f / m[p*4+p];
    m[p*4+p] = piv;
    #pragma unroll
    for (int c = 0; c < 4; ++c) if (c != p) m[p*4+c] *= piv;
    #pragma unroll
    for (int r = 0; r < 4; ++r) {
      if (r == p) continue;
      float f = m[r*4+p];
      #pragma unroll
      for (int c = 0; c < 4; ++c) if (c != p) m[r*4+c] = fmaf(-f, m[p*4+c], m[r*4+c]);
      m[r*4+p] = -f*piv;
    }
  }
}

// Block Gauss-Jordan, 4x4 pivots broadcast via LDS (sw[16]). NR rows x WDT cols (ld LD).
template<int NR, int LD, int WDT>
__device__ __forceinline__ void gjb4w(float* a, float* b, float* sw, int tid, int nth) {
  float* s = a; float* d = b;
  for (int kb = 0; kb < NR; kb += 4) {
    if (tid == 0) {
      float m[16];
      #pragma unroll
      for (int r = 0; r < 4; ++r)
        #pragma unroll
        for (int c = 0; c < 4; ++c) m[r*4+c] = s[(kb+r)*LD + kb + c];
      inv4ip(m);
      #pragma unroll
      for (int q = 0; q < 16; ++q) sw[q] = m[q];
    }
    lbar();
    {
      float w0=sw[0], w1=sw[1], w2=sw[2], w3=sw[3];
      float w4=sw[4], w5=sw[5], w6=sw[6], w7=sw[7];
      float w8=sw[8], w9=sw[9], w10=sw[10], w11=sw[11];
      float w12=sw[12], w13=sw[13], w14=sw[14], w15=sw[15];
      for (int e = tid; e < NR*WDT; e += nth) {
        int r = e / WDT, c = e - r*WDT;
        float v;
        if ((unsigned)(r - kb) < 4u) {
          const float* wr = sw + (r - kb)*4;
          v = wr[0]*s[kb*LD+c] + wr[1]*s[(kb+1)*LD+c]
            + wr[2]*s[(kb+2)*LD+c] + wr[3]*s[(kb+3)*LD+c];
        } else {
          float s0=s[r*LD+kb], s1=s[r*LD+kb+1], s2=s[r*LD+kb+2], s3=s[r*LD+kb+3];
          float l0 = s0*w0+s1*w4+s2*w8+s3*w12;
          float l1 = s0*w1+s1*w5+s2*w9+s3*w13;
          float l2 = s0*w2+s1*w6+s2*w10+s3*w14;
          float l3 = s0*w3+s1*w7+s2*w11+s3*w15;
          v = s[r*LD+c] - (l0*s[kb*LD+c] + l1*s[(kb+1)*LD+c] + l2*s[(kb+2)*LD+c] + l3*s[(kb+3)*LD+c]);
        }
        d[r*LD+c] = v;
      }
    }
    lbar();
    float* t2 = s; s = d; d = t2;
  }
}

// Fused GJ on THREE stacked 32x[M|I] systems (1024 thr, stride 2080, ld 65).
__device__ __forceinline__ void gj3_db(float* a, float* b, float* ldet0) {
  const int tid = threadIdx.x;
  for (int k = 0; k < 32; ++k) {
    float* src = (k & 1) ? b : a;
    float* dst = (k & 1) ? a : b;
    if (ldet0 != nullptr && tid == 0) *ldet0 += logf(fabsf(src[k*65 + k]));
    #pragma unroll
    for (int e = 0; e < 6; ++e) {
      int ee = tid + e*1024;
      int m = ee >> 11;
      int rr = (ee & 2047) >> 6;
      int c = ee & 63;
      int base = m*2080;
      float piv = src[base + k*65 + k];
      float pr = src[base + k*65 + c] / piv;
      float v = (rr == k) ? pr : fmaf(-src[base + rr*65 + k], pr, src[base + rr*65 + c]);
      dst[base + rr*65 + c] = v;
    }
    lbar();
  }
}

// Fused GJ: Qz (32, ld65) + Qx (16, ld33). 1024 thr, 32 rounds.
__device__ __forceinline__ void gjzx_db(float* qa, float* qb, float* xa, float* xb,
                                        float* ldz, float* ldx) {
  const int tid = threadIdx.x;
  for (int k = 0; k < 32; ++k) {
    float* qs = (k & 1) ? qb : qa;
    float* qd = (k & 1) ? qa : qb;
    if (tid == 0) *ldz += logf(fabsf(qs[k*65 + k]));
    if (tid == 1 && k < 16) {
      float* xs = (k & 1) ? xb : xa;
      *ldx += logf(fabsf(xs[k*33 + k]));
    }
    #pragma unroll
    for (int e = 0; e < 2; ++e) {
      int ee = tid + e*1024;
      int rr = ee >> 6, c = ee & 63;
      float piv = qs[k*65 + k];
      float pr = qs[k*65 + c] / piv;
      qd[rr*65 + c] = (rr == k) ? pr : fmaf(-qs[rr*65 + k], pr, qs[rr*65 + c]);
    }
    if (k < 16 && tid < 512) {
      float* xs = (k & 1) ? xb : xa;
      float* xd = (k & 1) ? xa : xb;
      int rr = tid >> 5, c = tid & 31;
      float piv = xs[k*33 + k];
      float pr = xs[k*33 + c] / piv;
      xd[rr*33 + c] = (rr == k) ? pr : fmaf(-xs[rr*33 + k], pr, xs[rr*33 + c]);
    }
    lbar();
  }
}

// block-wide double sum over 1024 threads. Valid on tid 0.
__device__ __forceinline__ double block_sum_d(double p, double* red) {
  #pragma unroll
  for (int o = 32; o > 0; o >>= 1) p += __shfl_down(p, o);
  const int tid = threadIdx.x;
  if ((tid & 63) == 0) red[tid >> 6] = p;
  lbar();
  double s = 0.0;
  if (tid == 0) {
    #pragma unroll
    for (int q = 0; q < 16; ++q) s += red[q];
  }
  lbar();
  return s;
}

// ======= forward Riccati (TS fixed iters, 1024 thr, 128-VGPR budget) + smoother consts =======
__global__ __launch_bounds__(1024, 4) void k_fwd2(
    const float* __restrict__ A, const float* __restrict__ C,
    const float* __restrict__ Q, const float* __restrict__ R,
    const float* __restrict__ m0, const float* __restrict__ P0,
    const float* __restrict__ x, float* __restrict__ out, float* __restrict__ wsp)
{
  __shared__ float sA[1056], sC[528], sQ[1056], sR[272], sCA[528];
  __shared__ float sPa[1056], sPb[1056], sV[1056], sT[1056];
  __shared__ float sW[528], sU1[1056], sU2[544];   // U2/K: 32x16, ld17
  __shared__ float aug[1296], aug2[1296];          // 16 x 81: [S | Z | Z2 | y]
  __shared__ float sm[32], smu[32], sxh[16], sxt[16];
  __shared__ float sMs[8448], sJ[1056], sX[1056], sU[1056], sT3[1056];
  __shared__ float augA[2080], augB[2080];
  __shared__ float swp[16];
  const int tid = threadIdx.x;
  const int i = tid >> 5, j = tid & 31;
  const int ij33 = i*33 + j;

  sA[ij33] = A[tid]; sQ[ij33] = Q[tid]; sPa[ij33] = P0[tid];
  if (tid < 512) sC[(tid>>5)*33 + (tid&31)] = C[tid];
  if (tid < 256) sR[(tid>>4)*17 + (tid&15)] = R[tid];
  if (tid < 32) sm[tid] = m0[tid];
  float xcur = 0.f, xnxt = 0.f;
  if (tid < 16) { xcur = x[(long)tid*NTT]; xnxt = x[(long)tid*NTT + 1]; }
  __syncthreads();
  // pre: CA = C@A (i<16) ; xh0 = C@m0
  if (i < 16) {
    float a0 = 0.f;
    #pragma unroll
    for (int k = 0; k < 32; ++k) a0 = fmaf(sC[i*33+k], sA[k*33+j], a0);
    sCA[ij33] = a0;
  }
  if (tid < 16) {
    float acc = 0.f;
    #pragma unroll
    for (int k = 0; k < 32; ++k) acc = fmaf(sC[tid*33+k], sm[k], acc);
    sxh[tid] = acc;
  }
  lbar();

  float* Pc = sPa; float* Pn = sPb;
  for (int t = 0; t < TS; ++t) {
    // R1: T=A@P (all) ; W=C@P (i<16) ; (t>0) m=A@mu, xh=CA@mu ; stage x
    if (tid < 16) sxt[tid] = xcur;
    {
      float acc = 0.f;
      #pragma unroll
      for (int k = 0; k < 32; ++k) acc = fmaf(sA[i*33+k], Pc[k*33+j], acc);
      sT[ij33] = acc;
    }
    if (i < 16) {
      float acc = 0.f;
      #pragma unroll
      for (int k = 0; k < 32; ++k) acc = fmaf(sC[i*33+k], Pc[k*33+j], acc);
      sW[ij33] = acc;
    }
    if (t > 0) {
      if (tid >= 992) {
        int r = tid - 992;
        float acc = 0.f;
        #pragma unroll
        for (int k = 0; k < 32; ++k) acc = fmaf(sA[r*33+k], smu[k], acc);
        sm[r] = acc;
      } else if (tid >= 976) {
        int r = tid - 976;
        float acc = 0.f;
        #pragma unroll
        for (int k = 0; k < 32; ++k) acc = fmaf(sCA[r*33+k], smu[k], acc);
        sxh[r] = acc;
      }
    }
    lbar();
    // R2: U1 = T@A^T + Q (all) ; aug = [S | W | U2^T | x-xh] ; sU2 = U2
    {
      float acc = sQ[ij33];
      #pragma unroll
      for (int k = 0; k < 32; ++k) acc = fmaf(sT[i*33+k], sA[j*33+k], acc);
      sU1[ij33] = acc;
    }
    if (tid < 256) {
      int r = tid >> 4, c = tid & 15;
      float acc = sR[r*17+c];
      #pragma unroll
      for (int k = 0; k < 32; ++k) acc = fmaf(sW[r*33+k], sC[c*33+k], acc);
      aug[r*81 + c] = acc;
    } else if (tid < 768) {
      int e = tid - 256;          // 0..511
      int r = e >> 5, c = e & 31;
      aug[r*81 + 16 + c] = sW[r*33+c];
      if (e < 16) aug[e*81 + 80] = sxt[e] - sxh[e];
    } else {
      int e = tid - 768;          // 0..255, two U2 entries each
      #pragma unroll
      for (int h = 0; h < 2; ++h) {
        int e2 = e + h*256;
        int r = e2 >> 5, c = e2 & 31;   // aug row r (0..15), U2^T col c (0..31)
        float acc = 0.f;
        #pragma unroll
        for (int k = 0; k < 32; ++k) acc = fmaf(sT[c*33+k], sC[r*33+k], acc);
        aug[r*81 + 48 + c] = acc;
        sU2[c*17 + r] = acc;            // U2[c][r] = (A P C^T)[c][r]
      }
    }
    lbar();
    gjb4w<16,81,81>(aug, aug2, swp, tid, 1024);   // aug -> [I | Z | Z2 | y]
    // R4: V = P - W^T Z ; Pn = sym(U1 - U2@Z2) two-sided ; mu = m + W^T y ; x rotate
    {
      float v  = Pc[ij33];
      float p  = sU1[ij33];
      float pT = sU1[j*33+i];
      #pragma unroll
      for (int q = 0; q < 16; ++q) {
        v  = fmaf(-sW[q*33+i],  aug[q*81+16+j], v);
        p  = fmaf(-sU2[i*17+q], aug[q*81+48+j], p);
        pT = fmaf(-sU2[j*17+q], aug[q*81+48+i], pT);
      }
      sV[ij33] = v;
      out[O_VF + (long)tid*NTT + t] = v;      // fire-and-forget
      Pn[ij33] = 0.5f*(p + pT);
    }
    if (tid < 32) {
      float acc = sm[tid];
      #pragma unroll
      for (int q = 0; q < 16; ++q) acc = fmaf(sW[q*33+tid], aug[q*81+80], acc);
      smu[tid] = acc;
      out[O_MUF + (long)tid*NTT + t] = acc;
    }
    if (tid < 16) { xcur = xnxt; xnxt = x[(long)tid*NTT + t + 2]; }
    lbar();
    { float* sw = Pc; Pc = Pn; Pn = sw; }
  }

  wsp[PW_VC + tid] = sV[ij33];
  wsp[PW_PC + tid] = Pc[ij33];
  if (tid < 32) wsp[PW_SMU + tid] = smu[tid];
  // K = Z^T (S symmetric => W^T Sinv == (Sinv W)^T)
  if (tid < 512) {
    int r = tid >> 4, c = tid & 15;
    float kv = aug[c*81 + 16 + r];
    sU2[r*17 + c] = kv;                 // reuse sU2 as K (32x16, ld17)
    wsp[PW_K + r*16 + c] = kv;
  }
  lbar();
  // E = A - K@CA
  {
    float e0 = sA[ij33];
    #pragma unroll
    for (int q = 0; q < 16; ++q) e0 = fmaf(-sU2[i*17+q], sCA[q*33+j], e0);
    wsp[PW_E + tid] = e0;
  }
  // ---- smoother constants ----
  for (int e = tid; e < 2048; e += 1024) {
    int r = e >> 6, c = e & 63;
    augA[r*65+c] = (c < 32) ? Pc[r*33+c] : ((c-32 == r) ? 1.f : 0.f);
  }
  lbar();
  gjb4w<32,65,64>(augA, augB, swp, tid, 1024);   // Pinv in right half of augA
  { // T3 = Vc@A^T
    float acc = 0.f;
    #pragma unroll
    for (int k = 0; k < 32; ++k) acc = fmaf(sV[i*33+k], sA[j*33+k], acc);
    sT3[ij33] = acc;
  }
  lbar();
  { // J = T3@Pinv
    float acc = 0.f;
    #pragma unroll
    for (int k = 0; k < 32; ++k) acc = fmaf(sT3[i*33+k], augA[k*65+32+j], acc);
    sJ[ij33] = acc;
  }
  lbar();
  wsp[PW_J + tid] = sJ[ij33];
  sMs[ij33] = sJ[ij33];
  { // D = I - J@A ; T3 = J@Pc
    float a0 = (i==j) ? 1.f : 0.f, b0 = 0.f;
    #pragma unroll
    for (int k = 0; k < 32; ++k) {
      a0 = fmaf(-sJ[i*33+k], sA[k*33+j], a0);
      b0 = fmaf(sJ[i*33+k], Pc[k*33+j], b0);
    }
    wsp[PW_D + tid] = a0;
    sT3[ij33] = b0;
  }
  lbar();
  { // X = Vc - T3@J^T
    float a0 = sV[ij33];
    #pragma unroll
    for (int k = 0; k < 32; ++k) a0 = fmaf(-sT3[i*33+k], sJ[j*33+k], a0);
    sX[ij33] = a0;
  }
  lbar();
  // pass 1 doubling: X (-> Vs_inf) with Ms chain
  for (int l = 0; l < 8; ++l) {
    const float* Ml = sMs + l*1056;
    { float acc = 0.f;
      #pragma unroll
      for (int k = 0; k < 32; ++k) acc = fmaf(Ml[i*33+k], sX[k*33+j], acc);
      sU[ij33] = acc; }
    lbar();
    { float a0 = sX[ij33], b0 = 0.f;
      #pragma unroll
      for (int k = 0; k < 32; ++k) {
        a0 = fmaf(sU[i*33+k], Ml[j*33+k], a0);
        b0 = fmaf(Ml[i*33+k], Ml[k*33+j], b0);
      }
      sX[ij33] = a0;
      if (l < 7) sMs[(l+1)*1056 + ij33] = b0;
    }
    lbar();
  }
  wsp[PW_VSINF + tid] = sX[ij33];
  // pass 2 doubling: Xd with Delta = Vc - Vs_inf (Ms reused); Xd aliases augB
  float* sXd = augB;
  sXd[ij33] = sV[ij33] - sX[ij33];
  lbar();
  for (int l = 0; l < 8; ++l) {
    const float* Ml = sMs + l*1056;
    { float acc = 0.f;
      #pragma unroll
      for (int k = 0; k < 32; ++k) acc = fmaf(Ml[i*33+k], sXd[k*33+j], acc);
      sU[ij33] = acc; }
    lbar();
    { float a0 = sXd[ij33];
      #pragma unroll
      for (int k = 0; k < 32; ++k) a0 = fmaf(sU[i*33+k], Ml[j*33+k], a0);
      sXd[ij33] = a0; }
    lbar();
  }
  { // V12_inf = J@Vs_inf
    float acc = 0.f;
    #pragma unroll
    for (int k = 0; k < 32; ++k) acc = fmaf(sJ[i*33+k], sX[k*33+j], acc);
    wsp[PW_V12INF + tid] = acc;
  }
  const float nt0f = (float)(NTT - TS);
  const float nt1f = (float)(NTT - 1 - TS);
  wsp[PW_SVSC + tid] = nt0f*sX[ij33] + sXd[ij33];
  sT3[ij33] = nt1f*sX[ij33] + sXd[ij33];
  lbar();
  {
    float acc = 0.f;
    #pragma unroll
    for (int k = 0; k < 32; ++k) acc = fmaf(sJ[i*33+k], sT3[k*33+j], acc);
    wsp[PW_SV12C + tid] = acc;
  }
}

// ---- 64-lane split helpers (4/2-accumulator trees) ----
__device__ __forceinline__ float mvp16(const float* m, float v, int b0) {
  float s0=0.f, s1=0.f, s2=0.f, s3=0.f;
  #pragma unroll
  for (int q = 0; q < 4; ++q) {
    s0 = fmaf(m[q],    __shfl(v, b0+q),    s0);
    s1 = fmaf(m[4+q],  __shfl(v, b0+4+q),  s1);
    s2 = fmaf(m[8+q],  __shfl(v, b0+8+q),  s2);
    s3 = fmaf(m[12+q], __shfl(v, b0+12+q), s3);
  }
  return (s0+s1)+(s2+s3);
}
__device__ __forceinline__ float mvp8(const float* m, float v, int b0) {
  float s0=0.f, s1=0.f;
  #pragma unroll
  for (int q = 0; q < 4; ++q) {
    s0 = fmaf(m[q],   __shfl(v, b0+q),   s0);
    s1 = fmaf(m[4+q], __shfl(v, b0+4+q), s1);
  }
  return s0+s1;
}

// ==== guarded forward mean scan: muf_s = E muf_{s-1} + K x_s ====
__global__ __launch_bounds__(64) void k_muf(const float* __restrict__ x, float* __restrict__ out, float* __restrict__ wsp) {
  __shared__ float sx[16*321];
  const int lane = threadIdx.x;
  const int sb = TS + (int)blockIdx.x * CHL;
  if (sb >= NTT) return;
  const int len = (NTT - sb < CHL) ? (NTT - sb) : CHL;
  int gs = (blockIdx.x == 0) ? sb : sb - GRD;
  if (gs < 0) gs = 0;
  const int total = sb + len - gs;   // <= 320
  for (int q = 0; q < 16; ++q)
    for (int idx = lane; idx < total; idx += 64)
      sx[q*321 + idx] = x[(long)q*NTT + gs + idx];
  const int r = lane & 31, bm = (lane & 32) >> 1, bx = (lane & 32) >> 2;
  float e[16], kx[8];
  #pragma unroll
  for (int q = 0; q < 16; ++q) e[q] = wsp[PW_E + r*32 + bm + q];
  #pragma unroll
  for (int q = 0; q < 8; ++q) kx[q] = wsp[PW_K + r*16 + bx + q];
  float mf = (blockIdx.x == 0) ? wsp[PW_SMU + r] : 0.f;
  lbar();
  float* po = out + O_MUF + (long)r*NTT;
  for (int s = 0; s < total; ++s) {
    float xq = sx[(lane&15)*321 + s];
    float acc = mvp16(e, mf, bm) + mvp8(kx, xq, bx);
    acc += __shfl_xor(acc, 32);
    mf = acc;
    int tg = gs + s;
    if (tg >= sb && lane < 32) po[tg] = mf;
  }
}

// ==== merged parallel kernel: vs_tail | head_par | fill | mus-scan by blockIdx ====
__global__ __launch_bounds__(1024, 4) void k_par1(
    const float* __restrict__ A, const float* __restrict__ Q,
    float* __restrict__ out, float* __restrict__ ws, float* __restrict__ wsp)
{
  __shared__ float sh[10400];
  __shared__ float swp[16];
  const int tid = threadIdx.x;
  const int i = tid >> 5, j = tid & 31;
  const int ij33 = i*33 + j;
  const int b = blockIdx.x;

  if (b < PB_HEAD) {
    // ---- vs_tail: Vs_{N-1-k} = Vs_inf + J^k Delta J^k^T ----
    const int k = b;
    float* sJ = sh; float* sM = sh+1056; float* sT = sh+2112; float* sDl = sh+3168; float* sVo = sh+4224;
    sJ[ij33] = wsp[PW_J + tid];
    sDl[ij33] = wsp[PW_VC + tid] - wsp[PW_VSINF + tid];
    const float vsi = wsp[PW_VSINF + tid];
    lbar();
    float vs;
    if (k == 0) {
      vs = vsi + sDl[ij33];
    } else {
      sM[ij33] = sJ[ij33];
      lbar();
      int hb = 31 - __builtin_clz((unsigned)k);
      for (int b2 = hb-1; b2 >= 0; --b2) {
        { float acc = 0.f;
          #pragma unroll
          for (int k2 = 0; k2 < 32; ++k2) acc = fmaf(sM[i*33+k2], sM[k2*33+j], acc);
          lbar(); sM[ij33] = acc; lbar(); }
        if ((k >> b2) & 1) {
          float acc = 0.f;
          #pragma unroll
          for (int k2 = 0; k2 < 32; ++k2) acc = fmaf(sM[i*33+k2], sJ[k2*33+j], acc);
          lbar(); sM[ij33] = acc; lbar();
        }
      }
      { float acc = 0.f;
        #pragma unroll
        for (int k2 = 0; k2 < 32; ++k2) acc = fmaf(sM[i*33+k2], sDl[k2*33+j], acc);
        sT[ij33] = acc; }
      lbar();
      { float acc = vsi;
        #pragma unroll
        for (int k2 = 0; k2 < 32; ++k2) acc = fmaf(sT[i*33+k2], sM[j*33+k2], acc);
        vs = acc; }
    }
    out[O_VS + (long)tid*NTT + (NTT-1-k)] = vs;
    sVo[ij33] = vs;
    lbar();
    if (k <= KTR-1) {
      float acc = 0.f;
      #pragma unroll
      for (int k2 = 0; k2 < 32; ++k2) acc = fmaf(sJ[i*33+k2], sVo[k2*33+j], acc);
      out[O_V12 + (long)tid*(NTT-1) + (NTT-2-k)] = acc;
    }
  } else if (b < PB_FILL) {
    // ---- head_par: per-t J_t, P_t (t < TS) ----
    const int tt = b - PB_HEAD;
    float* sA = sh; float* sQ2 = sh+1056; float* sVf = sh+2112; float* sAV = sh+3168; float* sP = sh+4224;
    float* aug = sh+5280; float* aug2 = sh+7360;
    sA[ij33] = A[tid]; sQ2[ij33] = Q[tid];
    sVf[ij33] = out[O_VF + (long)tid*NTT + tt];
    lbar();
    { float acc = 0.f;
      #pragma unroll
      for (int k2 = 0; k2 < 32; ++k2) acc = fmaf(sA[i*33+k2], sVf[k2*33+j], acc);
      sAV[ij33] = acc;
    }
    lbar();
    { float a1 = sQ2[ij33];
      float a2 = sQ2[j*33+i];
      #pragma unroll
      for (int k2 = 0; k2 < 32; ++k2) {
        a1 = fmaf(sAV[i*33+k2], sA[j*33+k2], a1);
        a2 = fmaf(sAV[j*33+k2], sA[i*33+k2], a2);
      }
      float ps = 0.5f*(a1 + a2);
      sP[ij33] = ps;
      aug[i*65+j] = ps; aug[i*65+32+j] = (i==j) ? 1.f : 0.f;
    }
    lbar();
    gjb4w<32,65,64>(aug, aug2, swp, tid, 1024);
    { float acc = 0.f;
      #pragma unroll
      for (int k2 = 0; k2 < 32; ++k2) acc = fmaf(sVf[i*33+k2], sA[j*33+k2], acc);
      sAV[ij33] = acc;
    }
    lbar();
    { float acc = 0.f;
      #pragma unroll
      for (int k2 = 0; k2 < 32; ++k2) acc = fmaf(sAV[i*33+k2], aug[k2*65+32+j], acc);
      ws[WS_JT + (long)tt*1024 + tid] = acc;
    }
    ws[WS_PT + (long)tt*1024 + tid] = sP[ij33];
  } else if (b < PB_MUS) {
    // ---- fill: one ij row, steady regions ----
    const int ij = b - PB_FILL;
    const int tb = NTT - 1 - KTR;
    const float vf = wsp[PW_VC + ij];
    const float vs = wsp[PW_VSINF + ij];
    const float v12 = wsp[PW_V12INF + ij];
    float* pvf = out + O_VF + (long)ij*NTT;
    float* pvs = out + O_VS + (long)ij*NTT;
    float* pv12 = out + O_V12 + (long)ij*(NTT-1);
    for (int t2 = TS + tid; t2 < NTT; t2 += 1024) pvf[t2] = vf;
    for (int t2 = TS + tid; t2 < tb; t2 += 1024) { pvs[t2] = vs; pv12[t2] = v12; }
  } else {
    // ---- guarded backward mean scan: mus_t = D muf_t + J mus_{t+1} ----
    const int c = b - PB_MUS;
    const int te = (NTT-1) - c*CHL;
    if (te <= TS) return;
    const int ts = (te - CHL > TS) ? (te - CHL) : TS;
    int start = te + GRD;
    if (start > NTT-1) start = NTT-1;
    const int total = start - ts + 1;   // <= 321
    float* smf = sh;                    // 32 x 321
    for (int e = tid; e < 32*total; e += 1024) {
      int q = e / total, idx = e - q*total;
      smf[q*321 + idx] = out[O_MUF + (long)q*NTT + ts + idx];
    }
    lbar();
    if (tid >= 64) return;
    const int lane = tid;
    const int r = lane & 31, bm = (lane & 32) >> 1;
    float dd[16], jj[16];
    #pragma unroll
    for (int q = 0; q < 16; ++q) { dd[q] = wsp[PW_D + r*32 + bm + q]; jj[q] = wsp[PW_J + r*32 + bm + q]; }
    float m;
    if (start == NTT-1) {
      m = smf[r*321 + (total-1)];       // mus_{N-1} = muf_{N-1} exact
      if (c == 0 && lane < 32) out[O_MUS + (long)r*NTT + (NTT-1)] = m;
    } else {
      m = 0.f;                          // guard: decays by rho^GRD before te
    }
    for (int tt = start-1; tt >= ts; --tt) {
      float mv = smf[r*321 + (tt - ts)];
      float acc = mvp16(dd, mv, bm) + mvp16(jj, m, bm);
      acc += __shfl_xor(acc, 32);
      m = acc;
      if (tt < te && lane < 32) out[O_MUS + (long)r*NTT + tt] = m;
    }
  }
}

// ======== head: serial recursion, 2 barrier rounds per step (TS steps) ========
__global__ __launch_bounds__(1024, 4) void k_head_ser(
    const float* __restrict__ A, float* __restrict__ out,
    float* __restrict__ ws, float* __restrict__ wsp)
{
  __shared__ float sA[32*33], sJa[32*33], sJb[32*33], sT1[32*33], sT2[32*33], sVs[32*33];
  __shared__ float smufT[32], sam[32], smsp[32];
  const int tid = threadIdx.x;
  const int i = tid >> 5, j = tid & 31;
  const int ij33 = i*33 + j;
  sA[ij33] = A[tid];
  float hsvs = 0.f, hsv12 = 0.f;
  {
    float vsinf = wsp[PW_VSINF + tid];
    int tt = TS - 1;
    float jc = ws[WS_JT + (long)tt*1024 + tid];
    float pc = ws[WS_PT + (long)tt*1024 + tid];
    float vfc = out[O_VF + (long)tid*NTT + tt];
    float mufc = (tid < 32) ? out[O_MUF + (long)tid*NTT + tt] : 0.f;
    if (tid < 32) smsp[tid] = out[O_MUS + (long)tid*NTT + TS];
    sVs[ij33] = vsinf;
    sJa[ij33] = jc;
    sT1[ij33] = vsinf - pc;
    if (tid < 32) smufT[tid] = mufc;
    lbar();
    float* Jc = sJa; float* Jn = sJb;
    for (; tt >= 0; --tt) {
      float jN = 0.f, pN = 0.f, vfN = 0.f, mufN = 0.f;
      if (tt > 0) {
        jN = ws[WS_JT + (long)(tt-1)*1024 + tid];
        pN = ws[WS_PT + (long)(tt-1)*1024 + tid];
        vfN = out[O_VF + (long)tid*NTT + (tt-1)];
        if (tid < 32) mufN = out[O_MUF + (long)tid*NTT + (tt-1)];
      }
      {
        float t2 = 0.f, v12 = 0.f;
        #pragma unroll
        for (int k2 = 0; k2 < 32; ++k2) {
          t2  = fmaf(Jc[i*33+k2], sT1[k2*33+j], t2);
          v12 = fmaf(Jc[i*33+k2], sVs[k2*33+j], v12);
        }
        sT2[ij33] = t2;
        out[O_V12 + (long)tid*(NTT-1) + tt] = v12;
        hsv12 += v12;
      }
      if (tid < 32) {
        float a = 0.f;
        #pragma unroll
        for (int k2 = 0; k2 < 32; ++k2) a = fmaf(sA[tid*33+k2], smufT[k2], a);
        sam[tid] = a;
      }
      lbar();
      {
        float vsn = vfc;
        #pragma unroll
        for (int k2 = 0; k2 < 32; ++k2) vsn = fmaf(sT2[i*33+k2], Jc[j*33+k2], vsn);
        out[O_VS + (long)tid*NTT + tt] = vsn;
        hsvs += vsn;
        sVs[ij33] = vsn;
        sT1[ij33] = vsn - pN;
        Jn[ij33] = jN;
      }
      if (tid < 32) {
        float mv = smufT[tid];
        #pragma unroll
        for (int k2 = 0; k2 < 32; ++k2) mv = fmaf(Jc[tid*33+k2], smsp[k2] - sam[k2], mv);
        out[O_MUS + (long)tid*NTT + tt] = mv;
        smsp[tid] = mv;
        smufT[tid] = mufN;
      }
      vfc = vfN;
      { float* sw = Jc; Jc = Jn; Jn = sw; }
      lbar();
    }
  }
  wsp[PW_HSVS + tid] = hsvs;
  wsp[PW_HSV12 + tid] = hsv12;
}

// gram partials: Gall, G12, Gx, xx per t-chunk
__global__ __launch_bounds__(256) void k_gram(const float* __restrict__ out, const float* __restrict__ x, float* __restrict__ ws) {
  __shared__ float smu[32][257];
  __shared__ float sx[256][16];
  const int b = blockIdx.x;
  const int t0 = b*256;
  for (int e = threadIdx.x; e < 32*257; e += 256) {
    int i2 = e/257, tt = e - i2*257;
    int t = t0 + tt;
    smu[i2][tt] = (t < NTT) ? out[O_MUS + (long)i2*NTT + t] : 0.f;
  }
  for (int e = threadIdx.x; e < 16*256; e += 256) {
    int j2 = e >> 8, tt = e & 255;
    sx[tt][j2] = x[(long)j2*NTT + t0 + tt];
  }
  __syncthreads();
  float* pb = ws + WS_GRAM + (long)b*GRAM_STRIDE;
  const int lim12 = (t0 + 256 <= NTT-1) ? 256 : (NTT-1-t0);
  for (int k = 0; k < 4; ++k) {
    int ij = threadIdx.x + k*256; int i2 = ij>>5, j2 = ij&31;
    float g = 0.f, g12 = 0.f;
    for (int tt = 0; tt < 256; ++tt) g = fmaf(smu[i2][tt], smu[j2][tt], g);
    for (int tt = 0; tt < lim12; ++tt) g12 = fmaf(smu[i2][tt], smu[j2][tt+1], g12);
    pb[ij] = g; pb[1024+ij] = g12;
  }
  for (int k = 0; k < 2; ++k) {
    int ij = threadIdx.x + k*256; int i2 = ij>>4, j2 = ij&15;
    float g = 0.f;
    for (int tt = 0; tt < 256; ++tt) g = fmaf(smu[i2][tt], sx[tt][j2], g);
    pb[2048+ij] = g;
  }
  {
    int ij = threadIdx.x; int i2 = ij>>4, j2 = ij&15;
    float g = 0.f;
    for (int tt = 0; tt < 256; ++tt) g = fmaf(sx[tt][i2], sx[tt][j2], g);
    pb[2560+ij] = g;
  }
}

// EM statistics + log-likelihood (fused GJ passes)
__global__ __launch_bounds__(1024, 4) void k_final(float* __restrict__ out, float* __restrict__ ws) {
  __shared__ float s_zz[1056], s_z11[1056], s_z12[1056], s_z22[1056];
  __shared__ float s_An[1056], s_T[1056], s_Qz[1056], s_W[1056];
  __shared__ float s_Gx[544], s_xx[272], s_Cn[528], s_U16[528], s_T16[272], s_Qx[272];
  __shared__ float a3[3*2080], b3[3*2080];
  __shared__ float qxa[528], qxb[528];
  __shared__ float s_mu0[32], s_muN[32];
  __shared__ float s_ld[3];
  __shared__ double s_red[16];
  const int tid = threadIdx.x;
  const int i = tid>>5, j = tid&31;
  const int ij33 = i*33+j;
  double ell_acc = 0.0;
  const double L2PI = 1.8378770664093454836;
  const float* wsp = ws + WS_PAR;

  float gall = 0.f, g12 = 0.f;
  for (int b = 0; b < 64; ++b) {
    gall += ws[WS_GRAM + (long)b*GRAM_STRIDE + tid];
    g12  += ws[WS_GRAM + (long)b*GRAM_STRIDE + 1024 + tid];
  }
  float svs  = wsp[PW_HSVS + tid] + wsp[PW_SVSC + tid];
  float sv12 = wsp[PW_HSV12 + tid] + wsp[PW_SV12C + tid];
  float vs0  = out[O_VS + (long)tid*NTT + 0];
  float vsN  = out[O_VS + (long)tid*NTT + (NTT-1)];
  if (tid < 512) { float g = 0.f; for (int b = 0; b < 64; ++b) g += ws[WS_GRAM + (long)b*GRAM_STRIDE + 2048 + tid]; s_Gx[(tid>>4)*17 + (tid&15)] = g; }
  if (tid < 256) { float g = 0.f; for (int b = 0; b < 64; ++b) g += ws[WS_GRAM + (long)b*GRAM_STRIDE + 2560 + tid]; s_xx[(tid>>4)*17 + (tid&15)] = g; }
  if (tid < 32) { s_mu0[tid] = out[O_MUS + (long)tid*NTT + 0]; s_muN[tid] = out[O_MUS + (long)tid*NTT + (NTT-1)]; }
  if (tid < 3) s_ld[tid] = 0.f;
  lbar();
  s_zz[ij33]  = gall + svs;
  s_z11[ij33] = (gall - s_muN[i]*s_muN[j]) + (svs - vsN);
  s_z22[ij33] = (gall - s_mu0[i]*s_mu0[j]) + (svs - vs0);
  s_z12[ij33] = g12 + sv12;
  s_W[ij33]   = vs0;
  lbar();

  {
    float p0n = 0.5f*(s_W[i*33+j] + s_W[j*33+i]);
    float a_  = s_mu0[i]*s_mu0[j];
    float aT  = s_mu0[j]*s_mu0[i];
    float u0  = ((a_ + s_W[ij33]) - (a_ + aT)) + a_;
    s_T[ij33] = u0;
    a3[i*65+j] = p0n;             a3[i*65+32+j] = (i==j) ? 1.f : 0.f;
    a3[2080 + i*65+j] = s_z11[ij33]; a3[2080 + i*65+32+j] = (i==j) ? 1.f : 0.f;
    a3[4160 + i*65+j] = s_zz[ij33];  a3[4160 + i*65+32+j] = (i==j) ? 1.f : 0.f;
  }
  lbar();
  { float q0 = 0.5f*(s_T[i*33+j] + s_T[j*33+i]); s_Qz[ij33] = q0; }
  lbar();
  gj3_db(a3, b3, &s_ld[0]);
  {
    double p = (double)a3[i*65+32+j] * (double)s_Qz[j*33+i];
    double tr = block_sum_d(p, s_red);
    if (tid == 0) ell_acc += -0.5*(32.0*L2PI + (double)s_ld[0]) - 0.5*tr;
  }

  {
    float acc = 0.f;
    #pragma unroll
    for (int k2 = 0; k2 < 32; ++k2) acc = fmaf(s_z12[k2*33+i], a3[2080 + k2*65+32+j], acc);
    s_An[ij33] = acc;
  }
  if (tid < 512) {
    int i16 = tid>>5, j32 = tid&31;
    float acc = 0.f;
    #pragma unroll
    for (int k2 = 0; k2 < 32; ++k2) acc = fmaf(s_Gx[k2*17+i16], a3[4160 + k2*65+32+j32], acc);
    s_Cn[i16*33+j32] = acc;
  }
  lbar();
  {
    float acc = 0.f;
    #pragma unroll
    for (int k2 = 0; k2 < 32; ++k2) acc = fmaf(s_An[i*33+k2], s_z12[k2*33+j], acc);
    s_T[ij33] = acc;
  }
  {
    float acc = 0.f;
    #pragma unroll
    for (int k2 = 0; k2 < 32; ++k2) acc = fmaf(s_An[i*33+k2], s_z11[k2*33+j], acc);
    s_W[ij33] = acc;
  }
  if (tid < 256) {
    int a2 = tid>>4, b2 = tid&15;
    float acc = 0.f;
    #pragma unroll
    for (int k2 = 0; k2 < 32; ++k2) acc = fmaf(s_Cn[a2*33+k2], s_Gx[k2*17+b2], acc);
    s_T16[a2*17+b2] = acc;
  }
  if (tid >= 512) {
    int tt2 = tid - 512;
    int i16 = tt2>>5, j32 = tt2&31;
    float acc = 0.f;
    #pragma unroll
    for (int k2 = 0; k2 < 32; ++k2) acc = fmaf(s_Cn[i16*33+k2], s_zz[k2*33+j32], acc);
    s_U16[i16*33+j32] = acc;
  }
  lbar();
  {
    float azza = 0.f;
    #pragma unroll
    for (int k2 = 0; k2 < 32; ++k2) azza = fmaf(s_W[i*33+k2], s_An[j*33+k2], azza);
    float u = (s_z22[ij33] - (s_T[i*33+j]+s_T[j*33+i])) + azza;
    s_Qz[ij33] = u;
  }
  if (tid < 256) {
    int a2 = tid>>4, b2 = tid&15;
    float czzc = 0.f;
    #pragma unroll
    for (int k2 = 0; k2 < 32; ++k2) czzc = fmaf(s_U16[a2*33+k2], s_Cn[b2*33+k2], czzc);
    float u = (s_xx[a2*17+b2] - (s_T16[a2*17+b2]+s_T16[b2*17+a2])) + czzc;
    s_Qx[a2*17+b2] = u;
  }
  lbar();
  {
    float qz = 0.5f*(s_Qz[i*33+j]+s_Qz[j*33+i]);
    s_T[ij33] = qz;
    a3[i*65+j] = qz/16383.0f; a3[i*65+32+j] = (i==j) ? 1.f : 0.f;
  }
  if (tid < 256) {
    int a2 = tid>>4, b2 = tid&15;
    float qx = 0.5f*(s_Qx[a2*17+b2]+s_Qx[b2*17+a2]);
    s_T16[a2*17+b2] = qx;
    qxa[a2*33+b2] = qx/16384.0f; qxa[a2*33+16+b2] = (a2==b2) ? 1.f : 0.f;
  }
  lbar();
  gjzx_db(a3, b3, qxa, qxb, &s_ld[1], &s_ld[2]);
  {
    double p = (double)a3[i*65+32+j] * (double)s_T[j*33+i];
    double tr = block_sum_d(p, s_red);
    if (tid == 0) ell_acc += -8191.5*(32.0*L2PI + (double)s_ld[1]) - 0.5*tr;
  }
  {
    double p = (i < 16 && j < 16) ? (double)qxa[i*33+16+j] * (double)s_T16[j*17+i] : 0.0;
    double tr = block_sum_d(p, s_red);
    if (tid == 0) {
      ell_acc += -8192.0*(16.0*L2PI + (double)s_ld[2]) - 0.5*tr;
      out[0] = (float)ell_acc;
    }
  }
}

extern "C" void kernel_launch(void* const* d_in, const int* in_sizes, int n_in,
                              void* d_out, int out_size, void* d_ws, size_t ws_size,
                              hipStream_t stream) {
  (void)in_sizes; (void)n_in; (void)out_size; (void)ws_size;
  const float* x  = (const float*)d_in[0];
  const float* A  = (const float*)d_in[1];
  const float* C  = (const float*)d_in[2];
  const float* Q  = (const float*)d_in[3];
  const float* R  = (const float*)d_in[4];
  const float* m0 = (const float*)d_in[5];
  const float* P0 = (const float*)d_in[6];
  float* out = (float*)d_out;
  float* ws  = (float*)d_ws;
  float* wsp = ws + WS_PAR;

  hipLaunchKernelGGL(k_fwd2, dim3(1), dim3(1024), 0, stream, A, C, Q, R, m0, P0, x, out, wsp);
  hipLaunchKernelGGL(k_muf, dim3(NCH), dim3(64), 0, stream, x, out, wsp);
  hipLaunchKernelGGL(k_par1, dim3(PB_END), dim3(1024), 0, stream, A, Q, out, ws, wsp);
  hipLaunchKernelGGL(k_head_ser, dim3(1), dim3(1024), 0, stream, A, out, ws, wsp);
  hipLaunchKernelGGL(k_gram, dim3(64), dim3(256), 0, stream, out, x, ws);
  hipLaunchKernelGGL(k_final, dim3(1), dim3(1024), 0, stream, out, ws);
}

// Round 14
// 712.118 us; speedup vs baseline: 1.0576x; 1.0576x over previous
//
#include <hip/hip_runtime.h>
#include <math.h>

#define NTT 16384
#define TS  32        // fixed forward transient length (freeze err ~1e-8 << fp32 noise)
#define KTR 32        // backward-transient tail length (closed form)
#define CHL 128       // chunk length for guarded parallel affine scans
#define GRD 192       // guard steps (rho^192 << tol)
#define NCH 128

// ---- output layout (floats) ----
static constexpr long O_MUF = 1;
static constexpr long O_VF  = O_MUF + 32L*NTT;
static constexpr long O_MUS = O_VF + 1024L*NTT;
static constexpr long O_VS  = O_MUS + 32L*NTT;
static constexpr long O_V12 = O_VS + 1024L*NTT;

// ---- workspace layout (floats) ----
static constexpr long WS_PT  = 0;              // P_t table: TS*1024
static constexpr long WS_PAR = 262144;
static constexpr int PW_VC=0, PW_PC=1024, PW_VSINF=2048, PW_V12INF=3072;
static constexpr int PW_E=4104, PW_K=6152, PW_SMU=6664;
static constexpr int PW_J=6696, PW_D=8744;
static constexpr int PW_HSVS=26152, PW_HSV12=27176, PW_SVSC=28200, PW_SV12C=29224;
static constexpr long WS_GRAM = WS_PAR + 30248;
static constexpr int  GRAM_STRIDE = 2816;
static constexpr long WS_JT = WS_GRAM;         // J_t table aliases GRAM (dead before k_gram)

// k_par1 role boundaries
static constexpr int PB_HEAD = KTR + 1;            // 33
static constexpr int PB_FILL = PB_HEAD + TS;       // 65
static constexpr int PB_MUS  = PB_FILL + 1024;     // 1089
static constexpr int PB_END  = PB_MUS + NCH;       // 1217

// LDS-only barrier: does NOT drain vmcnt -> global stores stay fire-and-forget.
__device__ __forceinline__ void lbar() {
  asm volatile("s_waitcnt lgkmcnt(0)" ::: "memory");
  __builtin_amdgcn_s_barrier();
}

// Single-pivot double-buffered GJ (SPD, no pivoting), aug [M|I], ld generic.
// 1 barrier per pivot; NO per-thread arrays (spill-free at 64-VGPR cap).
template<int n>
__device__ __forceinline__ void gj_db(float* a, float* b, int ld, float* ldet) {
  const int tid = threadIdx.x;
  const int nth = blockDim.x;
  for (int k = 0; k < n; ++k) {
    float* src = (k & 1) ? b : a;
    float* dst = (k & 1) ? a : b;
    if (ldet != nullptr && tid == 0) *ldet += logf(fabsf(src[k*ld + k]));
    for (int e = tid; e < 2*n*n; e += nth) {
      int r = e / (2*n), c = e - r*(2*n);
      float piv = src[k*ld + k];
      float pr = src[k*ld + c] / piv;
      float v = (r == k) ? pr : fmaf(-src[r*ld + k], pr, src[r*ld + c]);
      dst[r*ld + c] = v;
    }
    lbar();
  }
}

// Fused GJ on THREE stacked 32x[M|I] systems (1024 thr, stride 2080, ld 65).
__device__ __forceinline__ void gj3_db(float* a, float* b, float* ldet0) {
  const int tid = threadIdx.x;
  for (int k = 0; k < 32; ++k) {
    float* src = (k & 1) ? b : a;
    float* dst = (k & 1) ? a : b;
    if (ldet0 != nullptr && tid == 0) *ldet0 += logf(fabsf(src[k*65 + k]));
    #pragma unroll
    for (int e = 0; e < 6; ++e) {
      int ee = tid + e*1024;
      int m = ee >> 11;
      int rr = (ee & 2047) >> 6;
      int c = ee & 63;
      int base = m*2080;
      float piv = src[base + k*65 + k];
      float pr = src[base + k*65 + c] / piv;
      float v = (rr == k) ? pr : fmaf(-src[base + rr*65 + k], pr, src[base + rr*65 + c]);
      dst[base + rr*65 + c] = v;
    }
    lbar();
  }
}

// Fused GJ: Qz (32, ld65) + Qx (16, ld33). 1024 thr, 32 rounds.
__device__ __forceinline__ void gjzx_db(float* qa, float* qb, float* xa, float* xb,
                                        float* ldz, float* ldx) {
  const int tid = threadIdx.x;
  for (int k = 0; k < 32; ++k) {
    float* qs = (k & 1) ? qb : qa;
    float* qd = (k & 1) ? qa : qb;
    if (tid == 0) *ldz += logf(fabsf(qs[k*65 + k]));
    if (tid == 1 && k < 16) {
      float* xs = (k & 1) ? xb : xa;
      *ldx += logf(fabsf(xs[k*33 + k]));
    }
    #pragma unroll
    for (int e = 0; e < 2; ++e) {
      int ee = tid + e*1024;
      int rr = ee >> 6, c = ee & 63;
      float piv = qs[k*65 + k];
      float pr = qs[k*65 + c] / piv;
      qd[rr*65 + c] = (rr == k) ? pr : fmaf(-qs[rr*65 + k], pr, qs[rr*65 + c]);
    }
    if (k < 16 && tid < 512) {
      float* xs = (k & 1) ? xb : xa;
      float* xd = (k & 1) ? xa : xb;
      int rr = tid >> 5, c = tid & 31;
      float piv = xs[k*33 + k];
      float pr = xs[k*33 + c] / piv;
      xd[rr*33 + c] = (rr == k) ? pr : fmaf(-xs[rr*33 + k], pr, xs[rr*33 + c]);
    }
    lbar();
  }
}

// block-wide double sum over 1024 threads. Valid on tid 0.
__device__ __forceinline__ double block_sum_d(double p, double* red) {
  #pragma unroll
  for (int o = 32; o > 0; o >>= 1) p += __shfl_down(p, o);
  const int tid = threadIdx.x;
  if ((tid & 63) == 0) red[tid >> 6] = p;
  lbar();
  double s = 0.0;
  if (tid == 0) {
    #pragma unroll
    for (int q = 0; q < 16; ++q) s += red[q];
  }
  lbar();
  return s;
}

// ======= forward Riccati (R6 structure, TS fixed iters) + smoother constants =======
__global__ __launch_bounds__(1024) void k_fwd2(
    const float* __restrict__ A, const float* __restrict__ C,
    const float* __restrict__ Q, const float* __restrict__ R,
    const float* __restrict__ m0, const float* __restrict__ P0,
    const float* __restrict__ x, float* __restrict__ out, float* __restrict__ wsp)
{
  __shared__ float sA[1056], sC[528], sQ[1056], sR[272];
  __shared__ float sPa[1056], sPb[1056], sV[1056], sAV[1056];
  __shared__ float sCP[528], sKt[544], sAug[528], sAug2[528];
  __shared__ float sm[32], smu[32], sxh[16], sxt[16];
  __shared__ float sMs[8448], sJ[1056], sX[1056], sU[1056], sT3[1056];
  __shared__ float augA[2080], augB[2080];
  const int tid = threadIdx.x;
  const int i = tid >> 5, j = tid & 31;
  const int ij33 = i*33 + j;

  sA[ij33] = A[tid]; sQ[ij33] = Q[tid]; sPa[ij33] = P0[tid];
  if (tid < 512) sC[(tid>>5)*33 + (tid&31)] = C[tid];
  if (tid < 256) sR[(tid>>4)*17 + (tid&15)] = R[tid];
  if (tid < 32) sm[tid] = m0[tid];
  float xcur = 0.f, xnxt = 0.f;
  if (tid < 16) { xcur = x[(long)tid*NTT]; xnxt = x[(long)tid*NTT + 1]; }
  __syncthreads();
  float aj[32];
  #pragma unroll
  for (int k = 0; k < 32; ++k) aj[k] = sA[j*33+k];

  float* Pc = sPa; float* Pn = sPb;
  for (int t = 0; t < TS; ++t) {
    // A: CP = C@P (i<16) ; xh = C@m ; stage x
    if (tid < 16) sxt[tid] = xcur;
    if (i < 16) {
      float acc = 0.f;
      #pragma unroll
      for (int k = 0; k < 32; ++k) acc = fmaf(sC[i*33+k], Pc[k*33+j], acc);
      sCP[ij33] = acc;
    }
    if (tid >= 512 && tid < 528) {
      int q = tid - 512;
      float acc = 0.f;
      #pragma unroll
      for (int k = 0; k < 32; ++k) acc = fmaf(sC[q*33+k], sm[k], acc);
      sxh[q] = acc;
    }
    lbar();
    // B: S = CP@C^T + R (aug)
    if (i < 16 && j < 16) {
      float acc = sR[i*17+j];
      #pragma unroll
      for (int k = 0; k < 32; ++k) acc = fmaf(sCP[i*33+k], sC[j*33+k], acc);
      sAug[i*33+j] = acc;
      sAug[i*33+16+j] = (i==j) ? 1.f : 0.f;
    }
    lbar();
    gj_db<16>(sAug, sAug2, 33, nullptr);   // Sinv in right half of sAug
    // C: K rows
    if (j < 16) {
      float acc = 0.f;
      #pragma unroll
      for (int k = 0; k < 16; ++k) acc = fmaf(sCP[k*33+i], sAug[k*33+16+j], acc);
      sKt[i*17+j] = acc;
    }
    lbar();
    // D: mu ; V = P - K@CP ; stores
    if (tid < 32) {
      float acc = sm[tid];
      #pragma unroll
      for (int k = 0; k < 16; ++k) acc = fmaf(sKt[tid*17+k], sxt[k]-sxh[k], acc);
      smu[tid] = acc;
      out[O_MUF + (long)tid*NTT + t] = acc;
    }
    {
      float acc = Pc[ij33];
      #pragma unroll
      for (int k = 0; k < 16; ++k) acc = fmaf(-sKt[i*17+k], sCP[k*33+j], acc);
      sV[ij33] = acc;
      out[O_VF + (long)tid*NTT + t] = acc;   // fire-and-forget
    }
    lbar();
    // E: AV = A@V ; rotate x
    {
      float acc = 0.f;
      #pragma unroll
      for (int k = 0; k < 32; ++k) acc = fmaf(sA[i*33+k], sV[k*33+j], acc);
      sAV[ij33] = acc;
    }
    if (tid < 16) { xcur = xnxt; xnxt = x[(long)tid*NTT + t + 2]; }
    lbar();
    // F: Pn = AV@A^T + Q ; m = A@mu
    {
      float acc = sQ[ij33];
      #pragma unroll
      for (int k = 0; k < 32; ++k) acc = fmaf(sAV[i*33+k], aj[k], acc);
      Pn[ij33] = acc;
    }
    if (tid < 32) {
      float acc = 0.f;
      #pragma unroll
      for (int k = 0; k < 32; ++k) acc = fmaf(sA[tid*33+k], smu[k], acc);
      sm[tid] = acc;
    }
    lbar();
    { float* sw = Pc; Pc = Pn; Pn = sw; }
  }

  wsp[PW_VC + tid] = sV[ij33];
  wsp[PW_PC + tid] = Pc[ij33];
  if (tid < 32) wsp[PW_SMU + tid] = smu[tid];
  if (tid < 512) wsp[PW_K + tid] = sKt[(tid>>4)*17 + (tid&15)];
  // F = I - K@C (into sAV)
  {
    float acc = (i==j) ? 1.f : 0.f;
    #pragma unroll
    for (int k = 0; k < 16; ++k) acc = fmaf(-sKt[i*17+k], sC[k*33+j], acc);
    sAV[ij33] = acc;
  }
  lbar();
  // E = F@A
  {
    float acc = 0.f;
    #pragma unroll
    for (int k = 0; k < 32; ++k) acc = fmaf(sAV[i*33+k], sA[k*33+j], acc);
    wsp[PW_E + tid] = acc;
  }
  // ---- smoother constants (V_inf in sV, P_inf in Pc — resident) ----
  for (int e = tid; e < 2048; e += 1024) {
    int r = e >> 6, c = e & 63;
    augA[r*65+c] = (c < 32) ? Pc[r*33+c] : ((c-32 == r) ? 1.f : 0.f);
  }
  lbar();
  gj_db<32>(augA, augB, 65, nullptr);   // Pinv in right half of augA
  { // T3 = Vc@A^T
    float acc = 0.f;
    #pragma unroll
    for (int k = 0; k < 32; ++k) acc = fmaf(sV[i*33+k], aj[k], acc);
    sT3[ij33] = acc;
  }
  lbar();
  { // J = T3@Pinv
    float acc = 0.f;
    #pragma unroll
    for (int k = 0; k < 32; ++k) acc = fmaf(sT3[i*33+k], augA[k*65+32+j], acc);
    sJ[ij33] = acc;
  }
  lbar();
  wsp[PW_J + tid] = sJ[ij33];
  sMs[ij33] = sJ[ij33];
  { // D = I - J@A ; T3 = J@Pc
    float a0 = (i==j) ? 1.f : 0.f, b0 = 0.f;
    #pragma unroll
    for (int k = 0; k < 32; ++k) {
      a0 = fmaf(-sJ[i*33+k], sA[k*33+j], a0);
      b0 = fmaf(sJ[i*33+k], Pc[k*33+j], b0);
    }
    wsp[PW_D + tid] = a0;
    sT3[ij33] = b0;
  }
  lbar();
  { // X = Vc - T3@J^T
    float a0 = sV[ij33];
    #pragma unroll
    for (int k = 0; k < 32; ++k) a0 = fmaf(-sT3[i*33+k], sJ[j*33+k], a0);
    sX[ij33] = a0;
  }
  lbar();
  // pass 1 doubling: X (-> Vs_inf) with Ms chain
  for (int l = 0; l < 8; ++l) {
    const float* Ml = sMs + l*1056;
    { float acc = 0.f;
      #pragma unroll
      for (int k = 0; k < 32; ++k) acc = fmaf(Ml[i*33+k], sX[k*33+j], acc);
      sU[ij33] = acc; }
    lbar();
    { float a0 = sX[ij33], b0 = 0.f;
      #pragma unroll
      for (int k = 0; k < 32; ++k) {
        a0 = fmaf(sU[i*33+k], Ml[j*33+k], a0);
        b0 = fmaf(Ml[i*33+k], Ml[k*33+j], b0);
      }
      sX[ij33] = a0;
      if (l < 7) sMs[(l+1)*1056 + ij33] = b0;
    }
    lbar();
  }
  wsp[PW_VSINF + tid] = sX[ij33];
  // pass 2 doubling: Xd with Delta = Vc - Vs_inf (Ms reused); Xd aliases augB
  float* sXd = augB;
  sXd[ij33] = sV[ij33] - sX[ij33];
  lbar();
  for (int l = 0; l < 8; ++l) {
    const float* Ml = sMs + l*1056;
    { float acc = 0.f;
      #pragma unroll
      for (int k = 0; k < 32; ++k) acc = fmaf(Ml[i*33+k], sXd[k*33+j], acc);
      sU[ij33] = acc; }
    lbar();
    { float a0 = sXd[ij33];
      #pragma unroll
      for (int k = 0; k < 32; ++k) a0 = fmaf(sU[i*33+k], Ml[j*33+k], a0);
      sXd[ij33] = a0; }
    lbar();
  }
  { // V12_inf = J@Vs_inf
    float acc = 0.f;
    #pragma unroll
    for (int k = 0; k < 32; ++k) acc = fmaf(sJ[i*33+k], sX[k*33+j], acc);
    wsp[PW_V12INF + tid] = acc;
  }
  const float nt0f = (float)(NTT - TS);
  const float nt1f = (float)(NTT - 1 - TS);
  wsp[PW_SVSC + tid] = nt0f*sX[ij33] + sXd[ij33];
  sT3[ij33] = nt1f*sX[ij33] + sXd[ij33];
  lbar();
  {
    float acc = 0.f;
    #pragma unroll
    for (int k = 0; k < 32; ++k) acc = fmaf(sJ[i*33+k], sT3[k*33+j], acc);
    wsp[PW_SV12C + tid] = acc;
  }
}

// ---- 64-lane split helpers (4/2-accumulator trees) ----
__device__ __forceinline__ float mvp16(const float* m, float v, int b0) {
  float s0=0.f, s1=0.f, s2=0.f, s3=0.f;
  #pragma unroll
  for (int q = 0; q < 4; ++q) {
    s0 = fmaf(m[q],    __shfl(v, b0+q),    s0);
    s1 = fmaf(m[4+q],  __shfl(v, b0+4+q),  s1);
    s2 = fmaf(m[8+q],  __shfl(v, b0+8+q),  s2);
    s3 = fmaf(m[12+q], __shfl(v, b0+12+q), s3);
  }
  return (s0+s1)+(s2+s3);
}
__device__ __forceinline__ float mvp8(const float* m, float v, int b0) {
  float s0=0.f, s1=0.f;
  #pragma unroll
  for (int q = 0; q < 4; ++q) {
    s0 = fmaf(m[q],   __shfl(v, b0+q),   s0);
    s1 = fmaf(m[4+q], __shfl(v, b0+4+q), s1);
  }
  return s0+s1;
}

// ==== guarded forward mean scan: muf_s = E muf_{s-1} + K x_s ====
__global__ __launch_bounds__(64) void k_muf(const float* __restrict__ x, float* __restrict__ out, float* __restrict__ wsp) {
  __shared__ float sx[16*321];
  const int lane = threadIdx.x;
  const int sb = TS + (int)blockIdx.x * CHL;
  if (sb >= NTT) return;
  const int len = (NTT - sb < CHL) ? (NTT - sb) : CHL;
  int gs = (blockIdx.x == 0) ? sb : sb - GRD;
  if (gs < 0) gs = 0;
  const int total = sb + len - gs;   // <= 320
  for (int q = 0; q < 16; ++q)
    for (int idx = lane; idx < total; idx += 64)
      sx[q*321 + idx] = x[(long)q*NTT + gs + idx];
  const int r = lane & 31, bm = (lane & 32) >> 1, bx = (lane & 32) >> 2;
  float e[16], kx[8];
  #pragma unroll
  for (int q = 0; q < 16; ++q) e[q] = wsp[PW_E + r*32 + bm + q];
  #pragma unroll
  for (int q = 0; q < 8; ++q) kx[q] = wsp[PW_K + r*16 + bx + q];
  float mf = (blockIdx.x == 0) ? wsp[PW_SMU + r] : 0.f;
  lbar();
  float* po = out + O_MUF + (long)r*NTT;
  for (int s = 0; s < total; ++s) {
    float xq = sx[(lane&15)*321 + s];
    float acc = mvp16(e, mf, bm) + mvp8(kx, xq, bx);
    acc += __shfl_xor(acc, 32);
    mf = acc;
    int tg = gs + s;
    if (tg >= sb && lane < 32) po[tg] = mf;
  }
}

// ==== merged parallel kernel: vs_tail | head_par | fill | mus-scan by blockIdx ====
__global__ __launch_bounds__(1024) void k_par1(
    const float* __restrict__ A, const float* __restrict__ Q,
    float* __restrict__ out, float* __restrict__ ws, float* __restrict__ wsp)
{
  __shared__ float sh[10400];
  const int tid = threadIdx.x;
  const int i = tid >> 5, j = tid & 31;
  const int ij33 = i*33 + j;
  const int b = blockIdx.x;

  if (b < PB_HEAD) {
    // ---- vs_tail: Vs_{N-1-k} = Vs_inf + J^k Delta J^k^T ----
    const int k = b;
    float* sJ = sh; float* sM = sh+1056; float* sT = sh+2112; float* sDl = sh+3168; float* sVo = sh+4224;
    sJ[ij33] = wsp[PW_J + tid];
    sDl[ij33] = wsp[PW_VC + tid] - wsp[PW_VSINF + tid];
    const float vsi = wsp[PW_VSINF + tid];
    lbar();
    float vs;
    if (k == 0) {
      vs = vsi + sDl[ij33];
    } else {
      sM[ij33] = sJ[ij33];
      lbar();
      int hb = 31 - __builtin_clz((unsigned)k);
      for (int b2 = hb-1; b2 >= 0; --b2) {
        { float acc = 0.f;
          #pragma unroll
          for (int k2 = 0; k2 < 32; ++k2) acc = fmaf(sM[i*33+k2], sM[k2*33+j], acc);
          lbar(); sM[ij33] = acc; lbar(); }
        if ((k >> b2) & 1) {
          float acc = 0.f;
          #pragma unroll
          for (int k2 = 0; k2 < 32; ++k2) acc = fmaf(sM[i*33+k2], sJ[k2*33+j], acc);
          lbar(); sM[ij33] = acc; lbar();
        }
      }
      { float acc = 0.f;
        #pragma unroll
        for (int k2 = 0; k2 < 32; ++k2) acc = fmaf(sM[i*33+k2], sDl[k2*33+j], acc);
        sT[ij33] = acc; }
      lbar();
      { float acc = vsi;
        #pragma unroll
        for (int k2 = 0; k2 < 32; ++k2) acc = fmaf(sT[i*33+k2], sM[j*33+k2], acc);
        vs = acc; }
    }
    out[O_VS + (long)tid*NTT + (NTT-1-k)] = vs;
    sVo[ij33] = vs;
    lbar();
    if (k <= KTR-1) {
      float acc = 0.f;
      #pragma unroll
      for (int k2 = 0; k2 < 32; ++k2) acc = fmaf(sJ[i*33+k2], sVo[k2*33+j], acc);
      out[O_V12 + (long)tid*(NTT-1) + (NTT-2-k)] = acc;
    }
  } else if (b < PB_FILL) {
    // ---- head_par: per-t J_t, P_t (t < TS) ----
    const int tt = b - PB_HEAD;
    float* sA = sh; float* sQ2 = sh+1056; float* sVf = sh+2112; float* sAV = sh+3168; float* sP = sh+4224;
    float* aug = sh+5280; float* aug2 = sh+7360;
    sA[ij33] = A[tid]; sQ2[ij33] = Q[tid];
    sVf[ij33] = out[O_VF + (long)tid*NTT + tt];
    lbar();
    { float acc = 0.f;
      #pragma unroll
      for (int k2 = 0; k2 < 32; ++k2) acc = fmaf(sA[i*33+k2], sVf[k2*33+j], acc);
      sAV[ij33] = acc;
    }
    lbar();
    { float a1 = sQ2[ij33];
      float a2 = sQ2[j*33+i];
      #pragma unroll
      for (int k2 = 0; k2 < 32; ++k2) {
        a1 = fmaf(sAV[i*33+k2], sA[j*33+k2], a1);
        a2 = fmaf(sAV[j*33+k2], sA[i*33+k2], a2);
      }
      float ps = 0.5f*(a1 + a2);
      sP[ij33] = ps;
      aug[i*65+j] = ps; aug[i*65+32+j] = (i==j) ? 1.f : 0.f;
    }
    lbar();
    gj_db<32>(aug, aug2, 65, nullptr);
    { float acc = 0.f;
      #pragma unroll
      for (int k2 = 0; k2 < 32; ++k2) acc = fmaf(sVf[i*33+k2], sA[j*33+k2], acc);
      sAV[ij33] = acc;
    }
    lbar();
    { float acc = 0.f;
      #pragma unroll
      for (int k2 = 0; k2 < 32; ++k2) acc = fmaf(sAV[i*33+k2], aug[k2*65+32+j], acc);
      ws[WS_JT + (long)tt*1024 + tid] = acc;
    }
    ws[WS_PT + (long)tt*1024 + tid] = sP[ij33];
  } else if (b < PB_MUS) {
    // ---- fill: one ij row, steady regions ----
    const int ij = b - PB_FILL;
    const int tb = NTT - 1 - KTR;
    const float vf = wsp[PW_VC + ij];
    const float vs = wsp[PW_VSINF + ij];
    const float v12 = wsp[PW_V12INF + ij];
    float* pvf = out + O_VF + (long)ij*NTT;
    float* pvs = out + O_VS + (long)ij*NTT;
    float* pv12 = out + O_V12 + (long)ij*(NTT-1);
    for (int t2 = TS + tid; t2 < NTT; t2 += 1024) pvf[t2] = vf;
    for (int t2 = TS + tid; t2 < tb; t2 += 1024) { pvs[t2] = vs; pv12[t2] = v12; }
  } else {
    // ---- guarded backward mean scan: mus_t = D muf_t + J mus_{t+1} ----
    const int c = b - PB_MUS;
    const int te = (NTT-1) - c*CHL;
    if (te <= TS) return;
    const int ts = (te - CHL > TS) ? (te - CHL) : TS;
    int start = te + GRD;
    if (start > NTT-1) start = NTT-1;
    const int total = start - ts + 1;   // <= 321
    float* smf = sh;                    // 32 x 321
    for (int e = tid; e < 32*total; e += 1024) {
      int q = e / total, idx = e - q*total;
      smf[q*321 + idx] = out[O_MUF + (long)q*NTT + ts + idx];
    }
    lbar();
    if (tid >= 64) return;
    const int lane = tid;
    const int r = lane & 31, bm = (lane & 32) >> 1;
    float dd[16], jj[16];
    #pragma unroll
    for (int q = 0; q < 16; ++q) { dd[q] = wsp[PW_D + r*32 + bm + q]; jj[q] = wsp[PW_J + r*32 + bm + q]; }
    float m;
    if (start == NTT-1) {
      m = smf[r*321 + (total-1)];       // mus_{N-1} = muf_{N-1} exact
      if (c == 0 && lane < 32) out[O_MUS + (long)r*NTT + (NTT-1)] = m;
    } else {
      m = 0.f;                          // guard: decays by rho^GRD before te
    }
    for (int tt = start-1; tt >= ts; --tt) {
      float mv = smf[r*321 + (tt - ts)];
      float acc = mvp16(dd, mv, bm) + mvp16(jj, m, bm);
      acc += __shfl_xor(acc, 32);
      m = acc;
      if (tt < te && lane < 32) out[O_MUS + (long)r*NTT + tt] = m;
    }
  }
}

// ======== head: serial recursion, 2 barrier rounds per step (TS steps) ========
__global__ __launch_bounds__(1024) void k_head_ser(
    const float* __restrict__ A, float* __restrict__ out,
    float* __restrict__ ws, float* __restrict__ wsp)
{
  __shared__ float sA[32*33], sJa[32*33], sJb[32*33], sT1[32*33], sT2[32*33], sVs[32*33];
  __shared__ float smufT[32], sam[32], smsp[32];
  const int tid = threadIdx.x;
  const int i = tid >> 5, j = tid & 31;
  const int ij33 = i*33 + j;
  sA[ij33] = A[tid];
  float hsvs = 0.f, hsv12 = 0.f;
  {
    float vsinf = wsp[PW_VSINF + tid];
    int tt = TS - 1;
    float jc = ws[WS_JT + (long)tt*1024 + tid];
    float pc = ws[WS_PT + (long)tt*1024 + tid];
    float vfc = out[O_VF + (long)tid*NTT + tt];
    float mufc = (tid < 32) ? out[O_MUF + (long)tid*NTT + tt] : 0.f;
    if (tid < 32) smsp[tid] = out[O_MUS + (long)tid*NTT + TS];
    sVs[ij33] = vsinf;
    sJa[ij33] = jc;
    sT1[ij33] = vsinf - pc;
    if (tid < 32) smufT[tid] = mufc;
    lbar();
    float* Jc = sJa; float* Jn = sJb;
    for (; tt >= 0; --tt) {
      float jN = 0.f, pN = 0.f, vfN = 0.f, mufN = 0.f;
      if (tt > 0) {
        jN = ws[WS_JT + (long)(tt-1)*1024 + tid];
        pN = ws[WS_PT + (long)(tt-1)*1024 + tid];
        vfN = out[O_VF + (long)tid*NTT + (tt-1)];
        if (tid < 32) mufN = out[O_MUF + (long)tid*NTT + (tt-1)];
      }
      {
        float t2 = 0.f, v12 = 0.f;
        #pragma unroll
        for (int k2 = 0; k2 < 32; ++k2) {
          t2  = fmaf(Jc[i*33+k2], sT1[k2*33+j], t2);
          v12 = fmaf(Jc[i*33+k2], sVs[k2*33+j], v12);
        }
        sT2[ij33] = t2;
        out[O_V12 + (long)tid*(NTT-1) + tt] = v12;
        hsv12 += v12;
      }
      if (tid < 32) {
        float a = 0.f;
        #pragma unroll
        for (int k2 = 0; k2 < 32; ++k2) a = fmaf(sA[tid*33+k2], smufT[k2], a);
        sam[tid] = a;
      }
      lbar();
      {
        float vsn = vfc;
        #pragma unroll
        for (int k2 = 0; k2 < 32; ++k2) vsn = fmaf(sT2[i*33+k2], Jc[j*33+k2], vsn);
        out[O_VS + (long)tid*NTT + tt] = vsn;
        hsvs += vsn;
        sVs[ij33] = vsn;
        sT1[ij33] = vsn - pN;
        Jn[ij33] = jN;
      }
      if (tid < 32) {
        float mv = smufT[tid];
        #pragma unroll
        for (int k2 = 0; k2 < 32; ++k2) mv = fmaf(Jc[tid*33+k2], smsp[k2] - sam[k2], mv);
        out[O_MUS + (long)tid*NTT + tt] = mv;
        smsp[tid] = mv;
        smufT[tid] = mufN;
      }
      vfc = vfN;
      { float* sw = Jc; Jc = Jn; Jn = sw; }
      lbar();
    }
  }
  wsp[PW_HSVS + tid] = hsvs;
  wsp[PW_HSV12 + tid] = hsv12;
}

// gram partials: Gall, G12, Gx, xx per t-chunk
__global__ __launch_bounds__(256) void k_gram(const float* __restrict__ out, const float* __restrict__ x, float* __restrict__ ws) {
  __shared__ float smu[32][257];
  __shared__ float sx[256][16];
  const int b = blockIdx.x;
  const int t0 = b*256;
  for (int e = threadIdx.x; e < 32*257; e += 256) {
    int i2 = e/257, tt = e - i2*257;
    int t = t0 + tt;
    smu[i2][tt] = (t < NTT) ? out[O_MUS + (long)i2*NTT + t] : 0.f;
  }
  for (int e = threadIdx.x; e < 16*256; e += 256) {
    int j2 = e >> 8, tt = e & 255;
    sx[tt][j2] = x[(long)j2*NTT + t0 + tt];
  }
  __syncthreads();
  float* pb = ws + WS_GRAM + (long)b*GRAM_STRIDE;
  const int lim12 = (t0 + 256 <= NTT-1) ? 256 : (NTT-1-t0);
  for (int k = 0; k < 4; ++k) {
    int ij = threadIdx.x + k*256; int i2 = ij>>5, j2 = ij&31;
    float g = 0.f, g12 = 0.f;
    for (int tt = 0; tt < 256; ++tt) g = fmaf(smu[i2][tt], smu[j2][tt], g);
    for (int tt = 0; tt < lim12; ++tt) g12 = fmaf(smu[i2][tt], smu[j2][tt+1], g12);
    pb[ij] = g; pb[1024+ij] = g12;
  }
  for (int k = 0; k < 2; ++k) {
    int ij = threadIdx.x + k*256; int i2 = ij>>4, j2 = ij&15;
    float g = 0.f;
    for (int tt = 0; tt < 256; ++tt) g = fmaf(smu[i2][tt], sx[tt][j2], g);
    pb[2048+ij] = g;
  }
  {
    int ij = threadIdx.x; int i2 = ij>>4, j2 = ij&15;
    float g = 0.f;
    for (int tt = 0; tt < 256; ++tt) g = fmaf(sx[tt][i2], sx[tt][j2], g);
    pb[2560+ij] = g;
  }
}

// EM statistics + log-likelihood (fused GJ passes)
__global__ __launch_bounds__(1024) void k_final(float* __restrict__ out, float* __restrict__ ws) {
  __shared__ float s_zz[1056], s_z11[1056], s_z12[1056], s_z22[1056];
  __shared__ float s_An[1056], s_T[1056], s_Qz[1056], s_W[1056];
  __shared__ float s_Gx[544], s_xx[272], s_Cn[528], s_U16[528], s_T16[272], s_Qx[272];
  __shared__ float a3[3*2080], b3[3*2080];
  __shared__ float qxa[528], qxb[528];
  __shared__ float s_mu0[32], s_muN[32];
  __shared__ float s_ld[3];
  __shared__ double s_red[16];
  const int tid = threadIdx.x;
  const int i = tid>>5, j = tid&31;
  const int ij33 = i*33+j;
  double ell_acc = 0.0;
  const double L2PI = 1.8378770664093454836;
  const float* wsp = ws + WS_PAR;

  float gall = 0.f, g12 = 0.f;
  for (int b = 0; b < 64; ++b) {
    gall += ws[WS_GRAM + (long)b*GRAM_STRIDE + tid];
    g12  += ws[WS_GRAM + (long)b*GRAM_STRIDE + 1024 + tid];
  }
  float svs  = wsp[PW_HSVS + tid] + wsp[PW_SVSC + tid];
  float sv12 = wsp[PW_HSV12 + tid] + wsp[PW_SV12C + tid];
  float vs0  = out[O_VS + (long)tid*NTT + 0];
  float vsN  = out[O_VS + (long)tid*NTT + (NTT-1)];
  if (tid < 512) { float g = 0.f; for (int b = 0; b < 64; ++b) g += ws[WS_GRAM + (long)b*GRAM_STRIDE + 2048 + tid]; s_Gx[(tid>>4)*17 + (tid&15)] = g; }
  if (tid < 256) { float g = 0.f; for (int b = 0; b < 64; ++b) g += ws[WS_GRAM + (long)b*GRAM_STRIDE + 2560 + tid]; s_xx[(tid>>4)*17 + (tid&15)] = g; }
  if (tid < 32) { s_mu0[tid] = out[O_MUS + (long)tid*NTT + 0]; s_muN[tid] = out[O_MUS + (long)tid*NTT + (NTT-1)]; }
  if (tid < 3) s_ld[tid] = 0.f;
  lbar();
  s_zz[ij33]  = gall + svs;
  s_z11[ij33] = (gall - s_muN[i]*s_muN[j]) + (svs - vsN);
  s_z22[ij33] = (gall - s_mu0[i]*s_mu0[j]) + (svs - vs0);
  s_z12[ij33] = g12 + sv12;
  s_W[ij33]   = vs0;
  lbar();

  {
    float p0n = 0.5f*(s_W[i*33+j] + s_W[j*33+i]);
    float a_  = s_mu0[i]*s_mu0[j];
    float aT  = s_mu0[j]*s_mu0[i];
    float u0  = ((a_ + s_W[ij33]) - (a_ + aT)) + a_;
    s_T[ij33] = u0;
    a3[i*65+j] = p0n;             a3[i*65+32+j] = (i==j) ? 1.f : 0.f;
    a3[2080 + i*65+j] = s_z11[ij33]; a3[2080 + i*65+32+j] = (i==j) ? 1.f : 0.f;
    a3[4160 + i*65+j] = s_zz[ij33];  a3[4160 + i*65+32+j] = (i==j) ? 1.f : 0.f;
  }
  lbar();
  { float q0 = 0.5f*(s_T[i*33+j] + s_T[j*33+i]); s_Qz[ij33] = q0; }
  lbar();
  gj3_db(a3, b3, &s_ld[0]);
  {
    double p = (double)a3[i*65+32+j] * (double)s_Qz[j*33+i];
    double tr = block_sum_d(p, s_red);
    if (tid == 0) ell_acc += -0.5*(32.0*L2PI + (double)s_ld[0]) - 0.5*tr;
  }

  {
    float acc = 0.f;
    #pragma unroll
    for (int k2 = 0; k2 < 32; ++k2) acc = fmaf(s_z12[k2*33+i], a3[2080 + k2*65+32+j], acc);
    s_An[ij33] = acc;
  }
  if (tid < 512) {
    int i16 = tid>>5, j32 = tid&31;
    float acc = 0.f;
    #pragma unroll
    for (int k2 = 0; k2 < 32; ++k2) acc = fmaf(s_Gx[k2*17+i16], a3[4160 + k2*65+32+j32], acc);
    s_Cn[i16*33+j32] = acc;
  }
  lbar();
  {
    float acc = 0.f;
    #pragma unroll
    for (int k2 = 0; k2 < 32; ++k2) acc = fmaf(s_An[i*33+k2], s_z12[k2*33+j], acc);
    s_T[ij33] = acc;
  }
  {
    float acc = 0.f;
    #pragma unroll
    for (int k2 = 0; k2 < 32; ++k2) acc = fmaf(s_An[i*33+k2], s_z11[k2*33+j], acc);
    s_W[ij33] = acc;
  }
  if (tid < 256) {
    int a2 = tid>>4, b2 = tid&15;
    float acc = 0.f;
    #pragma unroll
    for (int k2 = 0; k2 < 32; ++k2) acc = fmaf(s_Cn[a2*33+k2], s_Gx[k2*17+b2], acc);
    s_T16[a2*17+b2] = acc;
  }
  if (tid >= 512) {
    int tt2 = tid - 512;
    int i16 = tt2>>5, j32 = tt2&31;
    float acc = 0.f;
    #pragma unroll
    for (int k2 = 0; k2 < 32; ++k2) acc = fmaf(s_Cn[i16*33+k2], s_zz[k2*33+j32], acc);
    s_U16[i16*33+j32] = acc;
  }
  lbar();
  {
    float azza = 0.f;
    #pragma unroll
    for (int k2 = 0; k2 < 32; ++k2) azza = fmaf(s_W[i*33+k2], s_An[j*33+k2], azza);
    float u = (s_z22[ij33] - (s_T[i*33+j]+s_T[j*33+i])) + azza;
    s_Qz[ij33] = u;
  }
  if (tid < 256) {
    int a2 = tid>>4, b2 = tid&15;
    float czzc = 0.f;
    #pragma unroll
    for (int k2 = 0; k2 < 32; ++k2) czzc = fmaf(s_U16[a2*33+k2], s_Cn[b2*33+k2], czzc);
    float u = (s_xx[a2*17+b2] - (s_T16[a2*17+b2]+s_T16[b2*17+a2])) + czzc;
    s_Qx[a2*17+b2] = u;
  }
  lbar();
  {
    float qz = 0.5f*(s_Qz[i*33+j]+s_Qz[j*33+i]);
    s_T[ij33] = qz;
    a3[i*65+j] = qz/16383.0f; a3[i*65+32+j] = (i==j) ? 1.f : 0.f;
  }
  if (tid < 256) {
    int a2 = tid>>4, b2 = tid&15;
    float qx = 0.5f*(s_Qx[a2*17+b2]+s_Qx[b2*17+a2]);
    s_T16[a2*17+b2] = qx;
    qxa[a2*33+b2] = qx/16384.0f; qxa[a2*33+16+b2] = (a2==b2) ? 1.f : 0.f;
  }
  lbar();
  gjzx_db(a3, b3, qxa, qxb, &s_ld[1], &s_ld[2]);
  {
    double p = (double)a3[i*65+32+j] * (double)s_T[j*33+i];
    double tr = block_sum_d(p, s_red);
    if (tid == 0) ell_acc += -8191.5*(32.0*L2PI + (double)s_ld[1]) - 0.5*tr;
  }
  {
    double p = (i < 16 && j < 16) ? (double)qxa[i*33+16+j] * (double)s_T16[j*17+i] : 0.0;
    double tr = block_sum_d(p, s_red);
    if (tid == 0) {
      ell_acc += -8192.0*(16.0*L2PI + (double)s_ld[2]) - 0.5*tr;
      out[0] = (float)ell_acc;
    }
  }
}

extern "C" void kernel_launch(void* const* d_in, const int* in_sizes, int n_in,
                              void* d_out, int out_size, void* d_ws, size_t ws_size,
                              hipStream_t stream) {
  (void)in_sizes; (void)n_in; (void)out_size; (void)ws_size;
  const float* x  = (const float*)d_in[0];
  const float* A  = (const float*)d_in[1];
  const float* C  = (const float*)d_in[2];
  const float* Q  = (const float*)d_in[3];
  const float* R  = (const float*)d_in[4];
  const float* m0 = (const float*)d_in[5];
  const float* P0 = (const float*)d_in[6];
  float* out = (float*)d_out;
  float* ws  = (float*)d_ws;
  float* wsp = ws + WS_PAR;

  hipLaunchKernelGGL(k_fwd2, dim3(1), dim3(1024), 0, stream, A, C, Q, R, m0, P0, x, out, wsp);
  hipLaunchKernelGGL(k_muf, dim3(NCH), dim3(64), 0, stream, x, out, wsp);
  hipLaunchKernelGGL(k_par1, dim3(PB_END), dim3(1024), 0, stream, A, Q, out, ws, wsp);
  hipLaunchKernelGGL(k_head_ser, dim3(1), dim3(1024), 0, stream, A, out, ws, wsp);
  hipLaunchKernelGGL(k_gram, dim3(64), dim3(256), 0, stream, out, x, ws);
  hipLaunchKernelGGL(k_final, dim3(1), dim3(1024), 0, stream, out, ws);
}

// Round 15
// 470.904 us; speedup vs baseline: 1.5994x; 1.5122x over previous
//
#include <hip/hip_runtime.h>
#include <math.h>

#define NTT 16384
#define PTOL 1e-5f
#define TCAP 48       // hard cap on forward transient length (t* ~43 measured at this tol)
#define KTR 32        // backward-transient tail length (closed form)
#define CHL 128       // chunk length for guarded parallel affine scans
#define GRD 192       // guard steps (rho^192 << tol)
#define NCH 128

// ---- output layout (floats) ----
static constexpr long O_MUF = 1;
static constexpr long O_VF  = O_MUF + 32L*NTT;
static constexpr long O_MUS = O_VF + 1024L*NTT;
static constexpr long O_VS  = O_MUS + 32L*NTT;
static constexpr long O_V12 = O_VS + 1024L*NTT;

// ---- workspace layout (floats) ----
static constexpr long WS_PT  = 0;              // P_t table: TCAP*1024
static constexpr long WS_PAR = 262144;
static constexpr int PW_VC=0, PW_PC=1024, PW_VSINF=2048, PW_V12INF=3072, PW_INTS=4096;
static constexpr int PW_E=4104, PW_EL=5128, PW_K=6152, PW_SMU=6664;
static constexpr int PW_J=6696, PW_D=8744;
static constexpr int PW_HSVS=26152, PW_HSV12=27176, PW_SVSC=28200, PW_SV12C=29224;
static constexpr long WS_GRAM = WS_PAR + 30248;
static constexpr int  GRAM_STRIDE = 2816;
static constexpr long WS_JT = WS_GRAM;         // J_t table aliases GRAM (dead before k_gram)

// k_par1 role boundaries
static constexpr int PB_HEAD = KTR + 1;            // 33
static constexpr int PB_FILL = PB_HEAD + TCAP;     // 81
static constexpr int PB_MUS  = PB_FILL + 1024;     // 1105
static constexpr int PB_END  = PB_MUS + NCH;       // 1233

// LDS-only barrier: does NOT drain vmcnt -> global stores stay fire-and-forget.
__device__ __forceinline__ void lbar() {
  asm volatile("s_waitcnt lgkmcnt(0)" ::: "memory");
  __builtin_amdgcn_s_barrier();
}

// Single-pivot double-buffered GJ (SPD, no pivoting), aug [M|I], ld generic.
template<int n>
__device__ __forceinline__ void gj_db(float* a, float* b, int ld, float* ldet) {
  const int tid = threadIdx.x;
  const int nth = blockDim.x;
  for (int k = 0; k < n; ++k) {
    float* src = (k & 1) ? b : a;
    float* dst = (k & 1) ? a : b;
    if (ldet != nullptr && tid == 0) *ldet += logf(fabsf(src[k*ld + k]));
    for (int e = tid; e < 2*n*n; e += nth) {
      int r = e / (2*n), c = e - r*(2*n);
      float piv = src[k*ld + k];
      float pr = src[k*ld + c] / piv;
      float v = (r == k) ? pr : fmaf(-src[r*ld + k], pr, src[r*ld + c]);
      dst[r*ld + c] = v;
    }
    lbar();
  }
}

// Fused GJ on THREE stacked 32x[M|I] systems (1024 thr, stride 2080, ld 65).
__device__ __forceinline__ void gj3_db(float* a, float* b, float* ldet0) {
  const int tid = threadIdx.x;
  for (int k = 0; k < 32; ++k) {
    float* src = (k & 1) ? b : a;
    float* dst = (k & 1) ? a : b;
    if (ldet0 != nullptr && tid == 0) *ldet0 += logf(fabsf(src[k*65 + k]));
    #pragma unroll
    for (int e = 0; e < 6; ++e) {
      int ee = tid + e*1024;
      int m = ee >> 11;
      int rr = (ee & 2047) >> 6;
      int c = ee & 63;
      int base = m*2080;
      float piv = src[base + k*65 + k];
      float pr = src[base + k*65 + c] / piv;
      float v = (rr == k) ? pr : fmaf(-src[base + rr*65 + k], pr, src[base + rr*65 + c]);
      dst[base + rr*65 + c] = v;
    }
    lbar();
  }
}

// Fused GJ: Qz (32, ld65) + Qx (16, ld33). 1024 thr, 32 rounds.
__device__ __forceinline__ void gjzx_db(float* qa, float* qb, float* xa, float* xb,
                                        float* ldz, float* ldx) {
  const int tid = threadIdx.x;
  for (int k = 0; k < 32; ++k) {
    float* qs = (k & 1) ? qb : qa;
    float* qd = (k & 1) ? qa : qb;
    if (tid == 0) *ldz += logf(fabsf(qs[k*65 + k]));
    if (tid == 1 && k < 16) {
      float* xs = (k & 1) ? xb : xa;
      *ldx += logf(fabsf(xs[k*33 + k]));
    }
    #pragma unroll
    for (int e = 0; e < 2; ++e) {
      int ee = tid + e*1024;
      int rr = ee >> 6, c = ee & 63;
      float piv = qs[k*65 + k];
      float pr = qs[k*65 + c] / piv;
      qd[rr*65 + c] = (rr == k) ? pr : fmaf(-qs[rr*65 + k], pr, qs[rr*65 + c]);
    }
    if (k < 16 && tid < 512) {
      float* xs = (k & 1) ? xb : xa;
      float* xd = (k & 1) ? xa : xb;
      int rr = tid >> 5, c = tid & 31;
      float piv = xs[k*33 + k];
      float pr = xs[k*33 + c] / piv;
      xd[rr*33 + c] = (rr == k) ? pr : fmaf(-xs[rr*33 + k], pr, xs[rr*33 + c]);
    }
    lbar();
  }
}

// block-wide double sum over 1024 threads. Valid on tid 0.
__device__ __forceinline__ double block_sum_d(double p, double* red) {
  #pragma unroll
  for (int o = 32; o > 0; o >>= 1) p += __shfl_down(p, o);
  const int tid = threadIdx.x;
  if ((tid & 63) == 0) red[tid >> 6] = p;
  lbar();
  double s = 0.0;
  if (tid == 0) {
    #pragma unroll
    for (int q = 0; q < 16; ++q) s += red[q];
  }
  lbar();
  return s;
}

// ======= forward: serial Riccati to convergence + smoother constants (R6 verbatim) =======
__global__ __launch_bounds__(1024) void k_fwd(
    const float* __restrict__ A, const float* __restrict__ C,
    const float* __restrict__ Q, const float* __restrict__ R,
    const float* __restrict__ m0, const float* __restrict__ P0,
    const float* __restrict__ x, float* __restrict__ out, float* __restrict__ wsp)
{
  __shared__ float sA[1056], sC[528], sQ[1056], sR[272];
  __shared__ float sPa[1056], sPb[1056], sV[1056], sAV[1056];
  __shared__ float sCP[528], sKt[544], sAug[528], sAug2[528];
  __shared__ float sm[32], smu[32], sxh[16], sxt[16];
  __shared__ float augA[2080], augB[2080], sMs[8448], sX[1056], sU[1056], sT[1056], sJ[1056];
  __shared__ int s_conv;
  const int tid = threadIdx.x;
  const int i = tid >> 5, j = tid & 31;
  const int ij33 = i*33 + j;

  sA[ij33] = A[tid]; sQ[ij33] = Q[tid]; sPa[ij33] = P0[tid];
  if (tid < 512) sC[(tid>>5)*33 + (tid&31)] = C[tid];
  if (tid < 256) sR[(tid>>4)*17 + (tid&15)] = R[tid];
  if (tid < 32) sm[tid] = m0[tid];
  float xcur = 0.f, xnxt = 0.f;
  if (tid < 16) { xcur = x[(long)tid*NTT + 0]; xnxt = x[(long)tid*NTT + 1]; }
  __syncthreads();
  float aj[32];
  #pragma unroll
  for (int k2 = 0; k2 < 32; ++k2) aj[k2] = sA[j*33+k2];

  float* Pc = sPa; float* Pn2 = sPb;
  int t = 0;
  for (; t < TCAP; ++t) {
    if (tid < 16) sxt[tid] = xcur;
    if (i < 16) {
      float acc = 0.f;
      #pragma unroll
      for (int k2 = 0; k2 < 32; ++k2) acc = fmaf(sC[i*33+k2], Pc[k2*33+j], acc);
      sCP[ij33] = acc;
    }
    if (tid >= 512 && tid < 528) {
      int q = tid - 512;
      float acc = 0.f;
      #pragma unroll
      for (int k2 = 0; k2 < 32; ++k2) acc = fmaf(sC[q*33+k2], sm[k2], acc);
      sxh[q] = acc;
    }
    lbar();
    if (i < 16 && j < 16) {
      float acc = sR[i*17+j];
      #pragma unroll
      for (int k2 = 0; k2 < 32; ++k2) acc = fmaf(sCP[i*33+k2], sC[j*33+k2], acc);
      sAug[i*33+j] = acc;
      sAug[i*33+16+j] = (i==j) ? 1.f : 0.f;
    }
    lbar();
    gj_db<16>(sAug, sAug2, 33, nullptr);   // Sinv in right half of sAug
    if (j < 16) {
      float acc = 0.f;
      #pragma unroll
      for (int k2 = 0; k2 < 16; ++k2) acc = fmaf(sCP[k2*33+i], sAug[k2*33+16+j], acc);
      sKt[i*17+j] = acc;
    }
    lbar();
    if (tid < 32) {
      float acc = sm[tid];
      #pragma unroll
      for (int k2 = 0; k2 < 16; ++k2) acc = fmaf(sKt[tid*17+k2], sxt[k2]-sxh[k2], acc);
      smu[tid] = acc;
      out[O_MUF + (long)tid*NTT + t] = acc;
    }
    {
      float acc = Pc[ij33];
      #pragma unroll
      for (int k2 = 0; k2 < 16; ++k2) acc = fmaf(-sKt[i*17+k2], sCP[k2*33+j], acc);
      sV[ij33] = acc;
      out[O_VF + (long)tid*NTT + t] = acc;   // fire-and-forget
    }
    if (tid == 0) s_conv = 1;
    lbar();
    {
      float acc = 0.f;
      #pragma unroll
      for (int k2 = 0; k2 < 32; ++k2) acc = fmaf(sA[i*33+k2], sV[k2*33+j], acc);
      sAV[ij33] = acc;
    }
    if (tid < 16) { xcur = xnxt; xnxt = x[(long)tid*NTT + t + 2]; }
    lbar();
    {
      float acc = sQ[ij33];
      #pragma unroll
      for (int k2 = 0; k2 < 32; ++k2) acc = fmaf(sAV[i*33+k2], aj[k2], acc);
      Pn2[ij33] = acc;
      if (fabsf(acc - Pc[ij33]) > PTOL) s_conv = 0;
    }
    if (tid < 32) {
      float acc = 0.f;
      #pragma unroll
      for (int k2 = 0; k2 < 32; ++k2) acc = fmaf(sA[tid*33+k2], smu[k2], acc);
      sm[tid] = acc;
    }
    lbar();
    int sc = s_conv;
    float* sw = Pc; Pc = Pn2; Pn2 = sw;      // Pc now P_{t+1}
    if (sc) { ++t; break; }
  }

  const int t_star = t;
  if (tid == 0) ((int*)(wsp + PW_INTS))[0] = t_star;
  wsp[PW_VC + tid] = sV[ij33];
  wsp[PW_PC + tid] = Pc[ij33];
  if (tid < 32) wsp[PW_SMU + tid] = smu[tid];
  if (tid < 512) wsp[PW_K + tid] = sKt[(tid>>4)*17 + (tid&15)];
  // F = I - K@C
  {
    float acc = (i==j) ? 1.f : 0.f;
    #pragma unroll
    for (int k2 = 0; k2 < 16; ++k2) acc = fmaf(-sKt[i*17+k2], sC[k2*33+j], acc);
    sAV[ij33] = acc;
  }
  lbar();
  // E = F@A
  {
    float acc = 0.f;
    #pragma unroll
    for (int k2 = 0; k2 < 32; ++k2) acc = fmaf(sAV[i*33+k2], sA[k2*33+j], acc);
    Pn2[ij33] = acc;
  }
  lbar();
  wsp[PW_E + tid] = Pn2[ij33];
  // E^CHL = E^128 via 7 squarings (ping-pong Pn2 <-> sAV)
  {
    float* cur = Pn2; float* tmp = sAV;
    for (int it = 0; it < 7; ++it) {
      float acc = 0.f;
      #pragma unroll
      for (int k2 = 0; k2 < 32; ++k2) acc = fmaf(cur[i*33+k2], cur[k2*33+j], acc);
      lbar();
      tmp[ij33] = acc;
      lbar();
      float* sw = cur; cur = tmp; tmp = sw;
    }
    wsp[PW_EL + tid] = cur[ij33];
  }

  // ======== smoother constants (V_inf in sV, P_inf in Pc — still resident) ========
  augA[i*65 + j] = Pc[ij33];
  augA[i*65 + 32 + j] = (i==j) ? 1.f : 0.f;
  lbar();
  gj_db<32>(augA, augB, 65, nullptr);   // Pc^{-1} in right half of augA
  { // T = Vc@A^T
    float acc = 0.f;
    #pragma unroll
    for (int k2 = 0; k2 < 32; ++k2) acc = fmaf(sV[i*33+k2], sA[j*33+k2], acc);
    sT[ij33] = acc;
  }
  lbar();
  { // J = T@Pinv
    float acc = 0.f;
    #pragma unroll
    for (int k2 = 0; k2 < 32; ++k2) acc = fmaf(sT[i*33+k2], augA[k2*65+32+j], acc);
    sJ[ij33] = acc;
  }
  lbar();
  wsp[PW_J + tid] = sJ[ij33];
  { // D = I - J@A
    float acc = (i==j) ? 1.f : 0.f;
    #pragma unroll
    for (int k2 = 0; k2 < 32; ++k2) acc = fmaf(-sJ[i*33+k2], sA[k2*33+j], acc);
    wsp[PW_D + tid] = acc;
  }
  sMs[ij33] = sJ[ij33];                 // Ms[0] = J
  { // T = J@Pc
    float acc = 0.f;
    #pragma unroll
    for (int k2 = 0; k2 < 32; ++k2) acc = fmaf(sJ[i*33+k2], Pc[k2*33+j], acc);
    sT[ij33] = acc;
  }
  lbar();
  { // X = B = Vc - T@J^T
    float acc = sV[ij33];
    #pragma unroll
    for (int k2 = 0; k2 < 32; ++k2) acc = fmaf(-sT[i*33+k2], sJ[j*33+k2], acc);
    sX[ij33] = acc;
  }
  lbar();
  // fused doubling: per level l: U = Ml@X ; X += U@Ml^T and Ms[l+1]=Ml@Ml
  for (int l = 0; l < 8; ++l) {
    const float* Ml = sMs + l*1056;
    { float acc = 0.f;
      #pragma unroll
      for (int k2 = 0; k2 < 32; ++k2) acc = fmaf(Ml[i*33+k2], sX[k2*33+j], acc);
      sU[ij33] = acc; }
    lbar();
    { float acc = sX[ij33];
      #pragma unroll
      for (int k2 = 0; k2 < 32; ++k2) acc = fmaf(sU[i*33+k2], Ml[j*33+k2], acc);
      sX[ij33] = acc; }
    if (l < 7) {
      float acc = 0.f;
      #pragma unroll
      for (int k2 = 0; k2 < 32; ++k2) acc = fmaf(Ml[i*33+k2], Ml[k2*33+j], acc);
      sMs[(l+1)*1056 + ij33] = acc;
    }
    lbar();
  }
  wsp[PW_VSINF + tid] = sX[ij33];          // Vs_inf
  // Xd doubling with Delta = Vc - Vs_inf (reuse Ms levels); sXd aliases augB
  float* sXd = augB;
  sXd[ij33] = sV[ij33] - sX[ij33];
  lbar();
  for (int l = 0; l < 8; ++l) {
    const float* Ml = sMs + l*1056;
    { float acc = 0.f;
      #pragma unroll
      for (int k2 = 0; k2 < 32; ++k2) acc = fmaf(Ml[i*33+k2], sXd[k2*33+j], acc);
      sU[ij33] = acc; }
    lbar();
    { float acc = sXd[ij33];
      #pragma unroll
      for (int k2 = 0; k2 < 32; ++k2) acc = fmaf(sU[i*33+k2], Ml[j*33+k2], acc);
      sXd[ij33] = acc; }
    lbar();
  }
  { // V12_inf = J@Vs_inf
    float acc = 0.f;
    #pragma unroll
    for (int k2 = 0; k2 < 32; ++k2) acc = fmaf(sJ[i*33+k2], sX[k2*33+j], acc);
    wsp[PW_V12INF + tid] = acc;
  }
  wsp[PW_SVSC + tid] = (float)(NTT - t_star)*sX[ij33] + sXd[ij33];
  sT[ij33] = (float)(NTT - 1 - t_star)*sX[ij33] + sXd[ij33];
  lbar();
  { float acc = 0.f;
    #pragma unroll
    for (int k2 = 0; k2 < 32; ++k2) acc = fmaf(sJ[i*33+k2], sT[k2*33+j], acc);
    wsp[PW_SV12C + tid] = acc;
  }
}

// ---- 64-lane split helpers (4/2-accumulator trees) ----
__device__ __forceinline__ float mvp16(const float* m, float v, int b0) {
  float s0=0.f, s1=0.f, s2=0.f, s3=0.f;
  #pragma unroll
  for (int q = 0; q < 4; ++q) {
    s0 = fmaf(m[q],    __shfl(v, b0+q),    s0);
    s1 = fmaf(m[4+q],  __shfl(v, b0+4+q),  s1);
    s2 = fmaf(m[8+q],  __shfl(v, b0+8+q),  s2);
    s3 = fmaf(m[12+q], __shfl(v, b0+12+q), s3);
  }
  return (s0+s1)+(s2+s3);
}
__device__ __forceinline__ float mvp8(const float* m, float v, int b0) {
  float s0=0.f, s1=0.f;
  #pragma unroll
  for (int q = 0; q < 4; ++q) {
    s0 = fmaf(m[q],   __shfl(v, b0+q),   s0);
    s1 = fmaf(m[4+q], __shfl(v, b0+4+q), s1);
  }
  return s0+s1;
}

// ==== guarded forward mean scan: muf_s = E muf_{s-1} + K x_s ====
__global__ __launch_bounds__(64) void k_muf(const float* __restrict__ x, float* __restrict__ out, float* __restrict__ wsp) {
  __shared__ float sx[16*321];
  const int lane = threadIdx.x;
  const int t_star = ((const int*)(wsp + PW_INTS))[0];
  const int sb = t_star + (int)blockIdx.x * CHL;
  if (sb >= NTT) return;
  const int len = (NTT - sb < CHL) ? (NTT - sb) : CHL;
  int gs = (blockIdx.x == 0) ? sb : sb - GRD;
  if (gs < 0) gs = 0;
  const int total = sb + len - gs;   // <= 320
  for (int q = 0; q < 16; ++q)
    for (int idx = lane; idx < total; idx += 64)
      sx[q*321 + idx] = x[(long)q*NTT + gs + idx];
  const int r = lane & 31, bm = (lane & 32) >> 1, bx = (lane & 32) >> 2;
  float e[16], kx[8];
  #pragma unroll
  for (int q = 0; q < 16; ++q) e[q] = wsp[PW_E + r*32 + bm + q];
  #pragma unroll
  for (int q = 0; q < 8; ++q) kx[q] = wsp[PW_K + r*16 + bx + q];
  float mf = (blockIdx.x == 0) ? wsp[PW_SMU + r] : 0.f;
  lbar();
  float* po = out + O_MUF + (long)r*NTT;
  for (int s = 0; s < total; ++s) {
    float xq = sx[(lane&15)*321 + s];
    float acc = mvp16(e, mf, bm) + mvp8(kx, xq, bx);
    acc += __shfl_xor(acc, 32);
    mf = acc;
    int tg = gs + s;
    if (tg >= sb && lane < 32) po[tg] = mf;
  }
}

// ==== merged parallel kernel: vs_tail | head_par | fill | mus-scan by blockIdx ====
__global__ __launch_bounds__(1024) void k_par1(
    const float* __restrict__ A, const float* __restrict__ Q,
    float* __restrict__ out, float* __restrict__ ws, float* __restrict__ wsp)
{
  __shared__ float sh[10400];
  const int tid = threadIdx.x;
  const int i = tid >> 5, j = tid & 31;
  const int ij33 = i*33 + j;
  const int b = blockIdx.x;
  const int t_star = ((const int*)(wsp + PW_INTS))[0];

  if (b < PB_HEAD) {
    // ---- vs_tail: Vs_{N-1-k} = Vs_inf + J^k Delta J^k^T ----
    const int k = b;
    float* sJ = sh; float* sM = sh+1056; float* sT = sh+2112; float* sDl = sh+3168; float* sVo = sh+4224;
    sJ[ij33] = wsp[PW_J + tid];
    sDl[ij33] = wsp[PW_VC + tid] - wsp[PW_VSINF + tid];
    const float vsi = wsp[PW_VSINF + tid];
    lbar();
    float vs;
    if (k == 0) {
      vs = vsi + sDl[ij33];
    } else {
      sM[ij33] = sJ[ij33];
      lbar();
      int hb = 31 - __builtin_clz((unsigned)k);
      for (int b2 = hb-1; b2 >= 0; --b2) {
        { float acc = 0.f;
          #pragma unroll
          for (int k2 = 0; k2 < 32; ++k2) acc = fmaf(sM[i*33+k2], sM[k2*33+j], acc);
          lbar(); sM[ij33] = acc; lbar(); }
        if ((k >> b2) & 1) {
          float acc = 0.f;
          #pragma unroll
          for (int k2 = 0; k2 < 32; ++k2) acc = fmaf(sM[i*33+k2], sJ[k2*33+j], acc);
          lbar(); sM[ij33] = acc; lbar();
        }
      }
      { float acc = 0.f;
        #pragma unroll
        for (int k2 = 0; k2 < 32; ++k2) acc = fmaf(sM[i*33+k2], sDl[k2*33+j], acc);
        sT[ij33] = acc; }
      lbar();
      { float acc = vsi;
        #pragma unroll
        for (int k2 = 0; k2 < 32; ++k2) acc = fmaf(sT[i*33+k2], sM[j*33+k2], acc);
        vs = acc; }
    }
    out[O_VS + (long)tid*NTT + (NTT-1-k)] = vs;
    sVo[ij33] = vs;
    lbar();
    if (k <= KTR-1) {
      float acc = 0.f;
      #pragma unroll
      for (int k2 = 0; k2 < 32; ++k2) acc = fmaf(sJ[i*33+k2], sVo[k2*33+j], acc);
      out[O_V12 + (long)tid*(NTT-1) + (NTT-2-k)] = acc;
    }
  } else if (b < PB_FILL) {
    // ---- head_par: per-t J_t, P_t ----
    const int tt = b - PB_HEAD;
    if (tt >= t_star) return;
    float* sA = sh; float* sQ2 = sh+1056; float* sVf = sh+2112; float* sAV = sh+3168; float* sP = sh+4224;
    float* aug = sh+5280; float* aug2 = sh+7360;
    sA[ij33] = A[tid]; sQ2[ij33] = Q[tid];
    sVf[ij33] = out[O_VF + (long)tid*NTT + tt];
    lbar();
    { float acc = 0.f;
      #pragma unroll
      for (int k2 = 0; k2 < 32; ++k2) acc = fmaf(sA[i*33+k2], sVf[k2*33+j], acc);
      sAV[ij33] = acc;
    }
    lbar();
    { float a1 = sQ2[ij33];
      float a2 = sQ2[j*33+i];
      #pragma unroll
      for (int k2 = 0; k2 < 32; ++k2) {
        a1 = fmaf(sAV[i*33+k2], sA[j*33+k2], a1);
        a2 = fmaf(sAV[j*33+k2], sA[i*33+k2], a2);
      }
      float ps = 0.5f*(a1 + a2);
      sP[ij33] = ps;
      aug[i*65+j] = ps; aug[i*65+32+j] = (i==j) ? 1.f : 0.f;
    }
    lbar();
    gj_db<32>(aug, aug2, 65, nullptr);
    { float acc = 0.f;
      #pragma unroll
      for (int k2 = 0; k2 < 32; ++k2) acc = fmaf(sVf[i*33+k2], sA[j*33+k2], acc);
      sAV[ij33] = acc;
    }
    lbar();
    { float acc = 0.f;
      #pragma unroll
      for (int k2 = 0; k2 < 32; ++k2) acc = fmaf(sAV[i*33+k2], aug[k2*65+32+j], acc);
      ws[WS_JT + (long)tt*1024 + tid] = acc;
    }
    ws[WS_PT + (long)tt*1024 + tid] = sP[ij33];
  } else if (b < PB_MUS) {
    // ---- fill: one ij row, steady regions ----
    const int ij = b - PB_FILL;
    const int tb = NTT - 1 - KTR;
    const float vf = wsp[PW_VC + ij];
    const float vs = wsp[PW_VSINF + ij];
    const float v12 = wsp[PW_V12INF + ij];
    float* pvf = out + O_VF + (long)ij*NTT;
    float* pvs = out + O_VS + (long)ij*NTT;
    float* pv12 = out + O_V12 + (long)ij*(NTT-1);
    for (int t2 = t_star + tid; t2 < NTT; t2 += 1024) pvf[t2] = vf;
    for (int t2 = t_star + tid; t2 < tb; t2 += 1024) { pvs[t2] = vs; pv12[t2] = v12; }
  } else {
    // ---- guarded backward mean scan: mus_t = D muf_t + J mus_{t+1} ----
    const int c = b - PB_MUS;
    const int te = (NTT-1) - c*CHL;
    if (te <= t_star) return;
    const int ts = (te - CHL > t_star) ? (te - CHL) : t_star;
    int start = te + GRD;
    if (start > NTT-1) start = NTT-1;
    const int total = start - ts + 1;   // <= 321
    float* smf = sh;                    // 32 x 321
    for (int e = tid; e < 32*total; e += 1024) {
      int q = e / total, idx = e - q*total;
      smf[q*321 + idx] = out[O_MUF + (long)q*NTT + ts + idx];
    }
    lbar();
    if (tid >= 64) return;
    const int lane = tid;
    const int r = lane & 31, bm = (lane & 32) >> 1;
    float dd[16], jj[16];
    #pragma unroll
    for (int q = 0; q < 16; ++q) { dd[q] = wsp[PW_D + r*32 + bm + q]; jj[q] = wsp[PW_J + r*32 + bm + q]; }
    float m;
    if (start == NTT-1) {
      m = smf[r*321 + (total-1)];       // mus_{N-1} = muf_{N-1} exact
      if (c == 0 && lane < 32) out[O_MUS + (long)r*NTT + (NTT-1)] = m;
    } else {
      m = 0.f;                          // guard: decays by rho^GRD before te
    }
    for (int tt = start-1; tt >= ts; --tt) {
      float mv = smf[r*321 + (tt - ts)];
      float acc = mvp16(dd, mv, bm) + mvp16(jj, m, bm);
      acc += __shfl_xor(acc, 32);
      m = acc;
      if (tt < te && lane < 32) out[O_MUS + (long)r*NTT + tt] = m;
    }
  }
}

// ======== head: serial recursion, 2 barrier rounds per step ========
__global__ __launch_bounds__(1024) void k_head_ser(
    const float* __restrict__ A, float* __restrict__ out,
    float* __restrict__ ws, float* __restrict__ wsp)
{
  __shared__ float sA[32*33], sJa[32*33], sJb[32*33], sT1[32*33], sT2[32*33], sVs[32*33];
  __shared__ float smufT[32], sam[32], smsp[32];
  const int tid = threadIdx.x;
  const int i = tid >> 5, j = tid & 31;
  const int ij33 = i*33 + j;
  const int t_star = ((const int*)(wsp + PW_INTS))[0];
  sA[ij33] = A[tid];
  float hsvs = 0.f, hsv12 = 0.f;
  if (t_star > 0) {
    float vsinf = wsp[PW_VSINF + tid];
    int tt = t_star - 1;
    float jc = ws[WS_JT + (long)tt*1024 + tid];
    float pc = ws[WS_PT + (long)tt*1024 + tid];
    float vfc = out[O_VF + (long)tid*NTT + tt];
    float mufc = (tid < 32) ? out[O_MUF + (long)tid*NTT + tt] : 0.f;
    if (tid < 32) smsp[tid] = out[O_MUS + (long)tid*NTT + t_star];
    sVs[ij33] = vsinf;
    sJa[ij33] = jc;
    sT1[ij33] = vsinf - pc;
    if (tid < 32) smufT[tid] = mufc;
    lbar();
    float* Jc = sJa; float* Jn = sJb;
    for (; tt >= 0; --tt) {
      float jN = 0.f, pN = 0.f, vfN = 0.f, mufN = 0.f;
      if (tt > 0) {
        jN = ws[WS_JT + (long)(tt-1)*1024 + tid];
        pN = ws[WS_PT + (long)(tt-1)*1024 + tid];
        vfN = out[O_VF + (long)tid*NTT + (tt-1)];
        if (tid < 32) mufN = out[O_MUF + (long)tid*NTT + (tt-1)];
      }
      {
        float t2 = 0.f, v12 = 0.f;
        #pragma unroll
        for (int k2 = 0; k2 < 32; ++k2) {
          t2  = fmaf(Jc[i*33+k2], sT1[k2*33+j], t2);
          v12 = fmaf(Jc[i*33+k2], sVs[k2*33+j], v12);
        }
        sT2[ij33] = t2;
        out[O_V12 + (long)tid*(NTT-1) + tt] = v12;
        hsv12 += v12;
      }
      if (tid < 32) {
        float a = 0.f;
        #pragma unroll
        for (int k2 = 0; k2 < 32; ++k2) a = fmaf(sA[tid*33+k2], smufT[k2], a);
        sam[tid] = a;
      }
      lbar();
      {
        float vsn = vfc;
        #pragma unroll
        for (int k2 = 0; k2 < 32; ++k2) vsn = fmaf(sT2[i*33+k2], Jc[j*33+k2], vsn);
        out[O_VS + (long)tid*NTT + tt] = vsn;
        hsvs += vsn;
        sVs[ij33] = vsn;
        sT1[ij33] = vsn - pN;
        Jn[ij33] = jN;
      }
      if (tid < 32) {
        float mv = smufT[tid];
        #pragma unroll
        for (int k2 = 0; k2 < 32; ++k2) mv = fmaf(Jc[tid*33+k2], smsp[k2] - sam[k2], mv);
        out[O_MUS + (long)tid*NTT + tt] = mv;
        smsp[tid] = mv;
        smufT[tid] = mufN;
      }
      vfc = vfN;
      { float* sw = Jc; Jc = Jn; Jn = sw; }
      lbar();
    }
  }
  wsp[PW_HSVS + tid] = hsvs;
  wsp[PW_HSV12 + tid] = hsv12;
}

// gram partials: Gall, G12, Gx, xx per t-chunk
__global__ __launch_bounds__(256) void k_gram(const float* __restrict__ out, const float* __restrict__ x, float* __restrict__ ws) {
  __shared__ float smu[32][257];
  __shared__ float sx[256][16];
  const int b = blockIdx.x;
  const int t0 = b*256;
  for (int e = threadIdx.x; e < 32*257; e += 256) {
    int i2 = e/257, tt = e - i2*257;
    int t = t0 + tt;
    smu[i2][tt] = (t < NTT) ? out[O_MUS + (long)i2*NTT + t] : 0.f;
  }
  for (int e = threadIdx.x; e < 16*256; e += 256) {
    int j2 = e >> 8, tt = e & 255;
    sx[tt][j2] = x[(long)j2*NTT + t0 + tt];
  }
  __syncthreads();
  float* pb = ws + WS_GRAM + (long)b*GRAM_STRIDE;
  const int lim12 = (t0 + 256 <= NTT-1) ? 256 : (NTT-1-t0);
  for (int k = 0; k < 4; ++k) {
    int ij = threadIdx.x + k*256; int i2 = ij>>5, j2 = ij&31;
    float g = 0.f, g12 = 0.f;
    for (int tt = 0; tt < 256; ++tt) g = fmaf(smu[i2][tt], smu[j2][tt], g);
    for (int tt = 0; tt < lim12; ++tt) g12 = fmaf(smu[i2][tt], smu[j2][tt+1], g12);
    pb[ij] = g; pb[1024+ij] = g12;
  }
  for (int k = 0; k < 2; ++k) {
    int ij = threadIdx.x + k*256; int i2 = ij>>4, j2 = ij&15;
    float g = 0.f;
    for (int tt = 0; tt < 256; ++tt) g = fmaf(smu[i2][tt], sx[tt][j2], g);
    pb[2048+ij] = g;
  }
  {
    int ij = threadIdx.x; int i2 = ij>>4, j2 = ij&15;
    float g = 0.f;
    for (int tt = 0; tt < 256; ++tt) g = fmaf(sx[tt][i2], sx[tt][j2], g);
    pb[2560+ij] = g;
  }
}

// EM statistics + log-likelihood (fused GJ passes)
__global__ __launch_bounds__(1024) void k_final(float* __restrict__ out, float* __restrict__ ws) {
  __shared__ float s_zz[1056], s_z11[1056], s_z12[1056], s_z22[1056];
  __shared__ float s_An[1056], s_T[1056], s_Qz[1056], s_W[1056];
  __shared__ float s_Gx[544], s_xx[272], s_Cn[528], s_U16[528], s_T16[272], s_Qx[272];
  __shared__ float a3[3*2080], b3[3*2080];
  __shared__ float qxa[528], qxb[528];
  __shared__ float s_mu0[32], s_muN[32];
  __shared__ float s_ld[3];
  __shared__ double s_red[16];
  const int tid = threadIdx.x;
  const int i = tid>>5, j = tid&31;
  const int ij33 = i*33+j;
  double ell_acc = 0.0;
  const double L2PI = 1.8378770664093454836;
  const float* wsp = ws + WS_PAR;

  float gall = 0.f, g12 = 0.f;
  for (int b = 0; b < 64; ++b) {
    gall += ws[WS_GRAM + (long)b*GRAM_STRIDE + tid];
    g12  += ws[WS_GRAM + (long)b*GRAM_STRIDE + 1024 + tid];
  }
  float svs  = wsp[PW_HSVS + tid] + wsp[PW_SVSC + tid];
  float sv12 = wsp[PW_HSV12 + tid] + wsp[PW_SV12C + tid];
  float vs0  = out[O_VS + (long)tid*NTT + 0];
  float vsN  = out[O_VS + (long)tid*NTT + (NTT-1)];
  if (tid < 512) { float g = 0.f; for (int b = 0; b < 64; ++b) g += ws[WS_GRAM + (long)b*GRAM_STRIDE + 2048 + tid]; s_Gx[(tid>>4)*17 + (tid&15)] = g; }
  if (tid < 256) { float g = 0.f; for (int b = 0; b < 64; ++b) g += ws[WS_GRAM + (long)b*GRAM_STRIDE + 2560 + tid]; s_xx[(tid>>4)*17 + (tid&15)] = g; }
  if (tid < 32) { s_mu0[tid] = out[O_MUS + (long)tid*NTT + 0]; s_muN[tid] = out[O_MUS + (long)tid*NTT + (NTT-1)]; }
  if (tid < 3) s_ld[tid] = 0.f;
  lbar();
  s_zz[ij33]  = gall + svs;
  s_z11[ij33] = (gall - s_muN[i]*s_muN[j]) + (svs - vsN);
  s_z22[ij33] = (gall - s_mu0[i]*s_mu0[j]) + (svs - vs0);
  s_z12[ij33] = g12 + sv12;
  s_W[ij33]   = vs0;
  lbar();

  {
    float p0n = 0.5f*(s_W[i*33+j] + s_W[j*33+i]);
    float a_  = s_mu0[i]*s_mu0[j];
    float aT  = s_mu0[j]*s_mu0[i];
    float u0  = ((a_ + s_W[ij33]) - (a_ + aT)) + a_;
    s_T[ij33] = u0;
    a3[i*65+j] = p0n;             a3[i*65+32+j] = (i==j) ? 1.f : 0.f;
    a3[2080 + i*65+j] = s_z11[ij33]; a3[2080 + i*65+32+j] = (i==j) ? 1.f : 0.f;
    a3[4160 + i*65+j] = s_zz[ij33];  a3[4160 + i*65+32+j] = (i==j) ? 1.f : 0.f;
  }
  lbar();
  { float q0 = 0.5f*(s_T[i*33+j] + s_T[j*33+i]); s_Qz[ij33] = q0; }
  lbar();
  gj3_db(a3, b3, &s_ld[0]);
  {
    double p = (double)a3[i*65+32+j] * (double)s_Qz[j*33+i];
    double tr = block_sum_d(p, s_red);
    if (tid == 0) ell_acc += -0.5*(32.0*L2PI + (double)s_ld[0]) - 0.5*tr;
  }

  {
    float acc = 0.f;
    #pragma unroll
    for (int k2 = 0; k2 < 32; ++k2) acc = fmaf(s_z12[k2*33+i], a3[2080 + k2*65+32+j], acc);
    s_An[ij33] = acc;
  }
  if (tid < 512) {
    int i16 = tid>>5, j32 = tid&31;
    float acc = 0.f;
    #pragma unroll
    for (int k2 = 0; k2 < 32; ++k2) acc = fmaf(s_Gx[k2*17+i16], a3[4160 + k2*65+32+j32], acc);
    s_Cn[i16*33+j32] = acc;
  }
  lbar();
  {
    float acc = 0.f;
    #pragma unroll
    for (int k2 = 0; k2 < 32; ++k2) acc = fmaf(s_An[i*33+k2], s_z12[k2*33+j], acc);
    s_T[ij33] = acc;
  }
  {
    float acc = 0.f;
    #pragma unroll
    for (int k2 = 0; k2 < 32; ++k2) acc = fmaf(s_An[i*33+k2], s_z11[k2*33+j], acc);
    s_W[ij33] = acc;
  }
  if (tid < 256) {
    int a2 = tid>>4, b2 = tid&15;
    float acc = 0.f;
    #pragma unroll
    for (int k2 = 0; k2 < 32; ++k2) acc = fmaf(s_Cn[a2*33+k2], s_Gx[k2*17+b2], acc);
    s_T16[a2*17+b2] = acc;
  }
  if (tid >= 512) {
    int tt2 = tid - 512;
    int i16 = tt2>>5, j32 = tt2&31;
    float acc = 0.f;
    #pragma unroll
    for (int k2 = 0; k2 < 32; ++k2) acc = fmaf(s_Cn[i16*33+k2], s_zz[k2*33+j32], acc);
    s_U16[i16*33+j32] = acc;
  }
  lbar();
  {
    float azza = 0.f;
    #pragma unroll
    for (int k2 = 0; k2 < 32; ++k2) azza = fmaf(s_W[i*33+k2], s_An[j*33+k2], azza);
    float u = (s_z22[ij33] - (s_T[i*33+j]+s_T[j*33+i])) + azza;
    s_Qz[ij33] = u;
  }
  if (tid < 256) {
    int a2 = tid>>4, b2 = tid&15;
    float czzc = 0.f;
    #pragma unroll
    for (int k2 = 0; k2 < 32; ++k2) czzc = fmaf(s_U16[a2*33+k2], s_Cn[b2*33+k2], czzc);
    float u = (s_xx[a2*17+b2] - (s_T16[a2*17+b2]+s_T16[b2*17+a2])) + czzc;
    s_Qx[a2*17+b2] = u;
  }
  lbar();
  {
    float qz = 0.5f*(s_Qz[i*33+j]+s_Qz[j*33+i]);
    s_T[ij33] = qz;
    a3[i*65+j] = qz/16383.0f; a3[i*65+32+j] = (i==j) ? 1.f : 0.f;
  }
  if (tid < 256) {
    int a2 = tid>>4, b2 = tid&15;
    float qx = 0.5f*(s_Qx[a2*17+b2]+s_Qx[b2*17+a2]);
    s_T16[a2*17+b2] = qx;
    qxa[a2*33+b2] = qx/16384.0f; qxa[a2*33+16+b2] = (a2==b2) ? 1.f : 0.f;
  }
  lbar();
  gjzx_db(a3, b3, qxa, qxb, &s_ld[1], &s_ld[2]);
  {
    double p = (double)a3[i*65+32+j] * (double)s_T[j*33+i];
    double tr = block_sum_d(p, s_red);
    if (tid == 0) ell_acc += -8191.5*(32.0*L2PI + (double)s_ld[1]) - 0.5*tr;
  }
  {
    double p = (i < 16 && j < 16) ? (double)qxa[i*33+16+j] * (double)s_T16[j*17+i] : 0.0;
    double tr = block_sum_d(p, s_red);
    if (tid == 0) {
      ell_acc += -8192.0*(16.0*L2PI + (double)s_ld[2]) - 0.5*tr;
      out[0] = (float)ell_acc;
    }
  }
}

extern "C" void kernel_launch(void* const* d_in, const int* in_sizes, int n_in,
                              void* d_out, int out_size, void* d_ws, size_t ws_size,
                              hipStream_t stream) {
  (void)in_sizes; (void)n_in; (void)out_size; (void)ws_size;
  const float* x  = (const float*)d_in[0];
  const float* A  = (const float*)d_in[1];
  const float* C  = (const float*)d_in[2];
  const float* Q  = (const float*)d_in[3];
  const float* R  = (const float*)d_in[4];
  const float* m0 = (const float*)d_in[5];
  const float* P0 = (const float*)d_in[6];
  float* out = (float*)d_out;
  float* ws  = (float*)d_ws;
  float* wsp = ws + WS_PAR;

  hipLaunchKernelGGL(k_fwd, dim3(1), dim3(1024), 0, stream, A, C, Q, R, m0, P0, x, out, wsp);
  hipLaunchKernelGGL(k_muf, dim3(NCH), dim3(64), 0, stream, x, out, wsp);
  hipLaunchKernelGGL(k_par1, dim3(PB_END), dim3(1024), 0, stream, A, Q, out, ws, wsp);
  hipLaunchKernelGGL(k_head_ser, dim3(1), dim3(1024), 0, stream, A, out, ws, wsp);
  hipLaunchKernelGGL(k_gram, dim3(64), dim3(256), 0, stream, out, x, ws);
  hipLaunchKernelGGL(k_final, dim3(1), dim3(1024), 0, stream, out, ws);
}

// Round 16
// 466.722 us; speedup vs baseline: 1.6137x; 1.0090x over previous
//
#include <hip/hip_runtime.h>
#include <math.h>

#define NTT 16384
#define PTOL 1e-5f
#define TCAP 48       // hard cap on forward transient length (t* ~43 measured at this tol)
#define KTR 32        // backward-transient tail length (closed form)
#define CHL 128       // chunk length for guarded parallel affine scans
#define GRD 192       // guard steps (rho^192 << tol)
#define NCH 128
#define NFCH 4        // fill chunks per row

// ---- output layout (floats) ----
static constexpr long O_MUF = 1;
static constexpr long O_VF  = O_MUF + 32L*NTT;
static constexpr long O_MUS = O_VF + 1024L*NTT;
static constexpr long O_VS  = O_MUS + 32L*NTT;
static constexpr long O_V12 = O_VS + 1024L*NTT;

// ---- workspace layout (floats) ----
static constexpr long WS_PT  = 0;              // P_t table: TCAP*1024
static constexpr long WS_PAR = 262144;
static constexpr int PW_VC=0, PW_PC=1024, PW_VSINF=2048, PW_V12INF=3072, PW_INTS=4096;
static constexpr int PW_E=4104, PW_EL=5128, PW_K=6152, PW_SMU=6664;
static constexpr int PW_J=6696, PW_D=8744;
static constexpr int PW_HSVS=26152, PW_HSV12=27176, PW_SVSC=28200, PW_SV12C=29224;
static constexpr long WS_GRAM = WS_PAR + 30248;
static constexpr int  GRAM_STRIDE = 2816;
static constexpr long WS_JT = WS_GRAM;         // J_t table aliases GRAM (dead before k_gram)

// k_par1 role boundaries
static constexpr int PB_HEAD = KTR + 1;            // 33
static constexpr int PB_FILL = PB_HEAD + TCAP;     // 81
static constexpr int PB_MUS  = PB_FILL + 1024*NFCH; // 4177
static constexpr int PB_END  = PB_MUS + NCH;       // 4305

// LDS-only barrier: does NOT drain vmcnt -> global stores stay fire-and-forget.
__device__ __forceinline__ void lbar() {
  asm volatile("s_waitcnt lgkmcnt(0)" ::: "memory");
  __builtin_amdgcn_s_barrier();
}

// vectorized constant fill of p[lo..hi) with 1024 threads (alignment-peeled float4)
__device__ __forceinline__ void fill4(float* p, int lo, int hi, float v, int tid) {
  if (lo >= hi) return;
  uintptr_t addr = (uintptr_t)(p + lo);
  int head = (int)(((16 - (addr & 15)) & 15) >> 2);
  int n = hi - lo;
  if (head > n) head = n;
  if (tid < head) p[lo + tid] = v;
  int vlo = lo + head;
  int nv = (hi - vlo) >> 2;
  if (nv > 0) {
    float4 vv; vv.x = v; vv.y = v; vv.z = v; vv.w = v;
    float4* q = (float4*)(p + vlo);
    for (int k = tid; k < nv; k += 1024) q[k] = vv;
  }
  int tlo = vlo + nv*4;
  if (tid < hi - tlo) p[tlo + tid] = v;
}

// Single-pivot double-buffered GJ (SPD, no pivoting), aug [M|I], ld generic.
template<int n>
__device__ __forceinline__ void gj_db(float* a, float* b, int ld, float* ldet) {
  const int tid = threadIdx.x;
  const int nth = blockDim.x;
  for (int k = 0; k < n; ++k) {
    float* src = (k & 1) ? b : a;
    float* dst = (k & 1) ? a : b;
    if (ldet != nullptr && tid == 0) *ldet += logf(fabsf(src[k*ld + k]));
    for (int e = tid; e < 2*n*n; e += nth) {
      int r = e / (2*n), c = e - r*(2*n);
      float piv = src[k*ld + k];
      float pr = src[k*ld + c] / piv;
      float v = (r == k) ? pr : fmaf(-src[r*ld + k], pr, src[r*ld + c]);
      dst[r*ld + c] = v;
    }
    lbar();
  }
}

// Fused GJ on THREE stacked 32x[M|I] systems (1024 thr, stride 2080, ld 65).
__device__ __forceinline__ void gj3_db(float* a, float* b, float* ldet0) {
  const int tid = threadIdx.x;
  for (int k = 0; k < 32; ++k) {
    float* src = (k & 1) ? b : a;
    float* dst = (k & 1) ? a : b;
    if (ldet0 != nullptr && tid == 0) *ldet0 += logf(fabsf(src[k*65 + k]));
    #pragma unroll
    for (int e = 0; e < 6; ++e) {
      int ee = tid + e*1024;
      int m = ee >> 11;
      int rr = (ee & 2047) >> 6;
      int c = ee & 63;
      int base = m*2080;
      float piv = src[base + k*65 + k];
      float pr = src[base + k*65 + c] / piv;
      float v = (rr == k) ? pr : fmaf(-src[base + rr*65 + k], pr, src[base + rr*65 + c]);
      dst[base + rr*65 + c] = v;
    }
    lbar();
  }
}

// Fused GJ: Qz (32, ld65) + Qx (16, ld33). 1024 thr, 32 rounds.
__device__ __forceinline__ void gjzx_db(float* qa, float* qb, float* xa, float* xb,
                                        float* ldz, float* ldx) {
  const int tid = threadIdx.x;
  for (int k = 0; k < 32; ++k) {
    float* qs = (k & 1) ? qb : qa;
    float* qd = (k & 1) ? qa : qb;
    if (tid == 0) *ldz += logf(fabsf(qs[k*65 + k]));
    if (tid == 1 && k < 16) {
      float* xs = (k & 1) ? xb : xa;
      *ldx += logf(fabsf(xs[k*33 + k]));
    }
    #pragma unroll
    for (int e = 0; e < 2; ++e) {
      int ee = tid + e*1024;
      int rr = ee >> 6, c = ee & 63;
      float piv = qs[k*65 + k];
      float pr = qs[k*65 + c] / piv;
      qd[rr*65 + c] = (rr == k) ? pr : fmaf(-qs[rr*65 + k], pr, qs[rr*65 + c]);
    }
    if (k < 16 && tid < 512) {
      float* xs = (k & 1) ? xb : xa;
      float* xd = (k & 1) ? xa : xb;
      int rr = tid >> 5, c = tid & 31;
      float piv = xs[k*33 + k];
      float pr = xs[k*33 + c] / piv;
      xd[rr*33 + c] = (rr == k) ? pr : fmaf(-xs[rr*33 + k], pr, xs[rr*33 + c]);
    }
    lbar();
  }
}

// block-wide double sum over 1024 threads. Valid on tid 0.
__device__ __forceinline__ double block_sum_d(double p, double* red) {
  #pragma unroll
  for (int o = 32; o > 0; o >>= 1) p += __shfl_down(p, o);
  const int tid = threadIdx.x;
  if ((tid & 63) == 0) red[tid >> 6] = p;
  lbar();
  double s = 0.0;
  if (tid == 0) {
    #pragma unroll
    for (int q = 0; q < 16; ++q) s += red[q];
  }
  lbar();
  return s;
}

// ======= forward: serial Riccati to convergence + smoother constants (R6 verbatim) =======
__global__ __launch_bounds__(1024) void k_fwd(
    const float* __restrict__ A, const float* __restrict__ C,
    const float* __restrict__ Q, const float* __restrict__ R,
    const float* __restrict__ m0, const float* __restrict__ P0,
    const float* __restrict__ x, float* __restrict__ out, float* __restrict__ wsp)
{
  __shared__ float sA[1056], sC[528], sQ[1056], sR[272];
  __shared__ float sPa[1056], sPb[1056], sV[1056], sAV[1056];
  __shared__ float sCP[528], sKt[544], sAug[528], sAug2[528];
  __shared__ float sm[32], smu[32], sxh[16], sxt[16];
  __shared__ float augA[2080], augB[2080], sMs[8448], sX[1056], sU[1056], sT[1056], sJ[1056];
  __shared__ int s_conv;
  const int tid = threadIdx.x;
  const int i = tid >> 5, j = tid & 31;
  const int ij33 = i*33 + j;

  sA[ij33] = A[tid]; sQ[ij33] = Q[tid]; sPa[ij33] = P0[tid];
  if (tid < 512) sC[(tid>>5)*33 + (tid&31)] = C[tid];
  if (tid < 256) sR[(tid>>4)*17 + (tid&15)] = R[tid];
  if (tid < 32) sm[tid] = m0[tid];
  float xcur = 0.f, xnxt = 0.f;
  if (tid < 16) { xcur = x[(long)tid*NTT + 0]; xnxt = x[(long)tid*NTT + 1]; }
  __syncthreads();
  float aj[32];
  #pragma unroll
  for (int k2 = 0; k2 < 32; ++k2) aj[k2] = sA[j*33+k2];

  float* Pc = sPa; float* Pn2 = sPb;
  int t = 0;
  for (; t < TCAP; ++t) {
    if (tid < 16) sxt[tid] = xcur;
    if (i < 16) {
      float acc = 0.f;
      #pragma unroll
      for (int k2 = 0; k2 < 32; ++k2) acc = fmaf(sC[i*33+k2], Pc[k2*33+j], acc);
      sCP[ij33] = acc;
    }
    if (tid >= 512 && tid < 528) {
      int q = tid - 512;
      float acc = 0.f;
      #pragma unroll
      for (int k2 = 0; k2 < 32; ++k2) acc = fmaf(sC[q*33+k2], sm[k2], acc);
      sxh[q] = acc;
    }
    lbar();
    if (i < 16 && j < 16) {
      float acc = sR[i*17+j];
      #pragma unroll
      for (int k2 = 0; k2 < 32; ++k2) acc = fmaf(sCP[i*33+k2], sC[j*33+k2], acc);
      sAug[i*33+j] = acc;
      sAug[i*33+16+j] = (i==j) ? 1.f : 0.f;
    }
    lbar();
    gj_db<16>(sAug, sAug2, 33, nullptr);   // Sinv in right half of sAug
    if (j < 16) {
      float acc = 0.f;
      #pragma unroll
      for (int k2 = 0; k2 < 16; ++k2) acc = fmaf(sCP[k2*33+i], sAug[k2*33+16+j], acc);
      sKt[i*17+j] = acc;
    }
    lbar();
    if (tid < 32) {
      float acc = sm[tid];
      #pragma unroll
      for (int k2 = 0; k2 < 16; ++k2) acc = fmaf(sKt[tid*17+k2], sxt[k2]-sxh[k2], acc);
      smu[tid] = acc;
      out[O_MUF + (long)tid*NTT + t] = acc;
    }
    {
      float acc = Pc[ij33];
      #pragma unroll
      for (int k2 = 0; k2 < 16; ++k2) acc = fmaf(-sKt[i*17+k2], sCP[k2*33+j], acc);
      sV[ij33] = acc;
      out[O_VF + (long)tid*NTT + t] = acc;   // fire-and-forget
    }
    if (tid == 0) s_conv = 1;
    lbar();
    {
      float acc = 0.f;
      #pragma unroll
      for (int k2 = 0; k2 < 32; ++k2) acc = fmaf(sA[i*33+k2], sV[k2*33+j], acc);
      sAV[ij33] = acc;
    }
    if (tid < 16) { xcur = xnxt; xnxt = x[(long)tid*NTT + t + 2]; }
    lbar();
    {
      float acc = sQ[ij33];
      #pragma unroll
      for (int k2 = 0; k2 < 32; ++k2) acc = fmaf(sAV[i*33+k2], aj[k2], acc);
      Pn2[ij33] = acc;
      if (fabsf(acc - Pc[ij33]) > PTOL) s_conv = 0;
    }
    if (tid < 32) {
      float acc = 0.f;
      #pragma unroll
      for (int k2 = 0; k2 < 32; ++k2) acc = fmaf(sA[tid*33+k2], smu[k2], acc);
      sm[tid] = acc;
    }
    lbar();
    int sc = s_conv;
    float* sw = Pc; Pc = Pn2; Pn2 = sw;      // Pc now P_{t+1}
    if (sc) { ++t; break; }
  }

  const int t_star = t;
  if (tid == 0) ((int*)(wsp + PW_INTS))[0] = t_star;
  wsp[PW_VC + tid] = sV[ij33];
  wsp[PW_PC + tid] = Pc[ij33];
  if (tid < 32) wsp[PW_SMU + tid] = smu[tid];
  if (tid < 512) wsp[PW_K + tid] = sKt[(tid>>4)*17 + (tid&15)];
  // F = I - K@C
  {
    float acc = (i==j) ? 1.f : 0.f;
    #pragma unroll
    for (int k2 = 0; k2 < 16; ++k2) acc = fmaf(-sKt[i*17+k2], sC[k2*33+j], acc);
    sAV[ij33] = acc;
  }
  lbar();
  // E = F@A
  {
    float acc = 0.f;
    #pragma unroll
    for (int k2 = 0; k2 < 32; ++k2) acc = fmaf(sAV[i*33+k2], sA[k2*33+j], acc);
    Pn2[ij33] = acc;
  }
  lbar();
  wsp[PW_E + tid] = Pn2[ij33];
  // E^CHL = E^128 via 7 squarings (ping-pong Pn2 <-> sAV)
  {
    float* cur = Pn2; float* tmp = sAV;
    for (int it = 0; it < 7; ++it) {
      float acc = 0.f;
      #pragma unroll
      for (int k2 = 0; k2 < 32; ++k2) acc = fmaf(cur[i*33+k2], cur[k2*33+j], acc);
      lbar();
      tmp[ij33] = acc;
      lbar();
      float* sw = cur; cur = tmp; tmp = sw;
    }
    wsp[PW_EL + tid] = cur[ij33];
  }

  // ======== smoother constants (V_inf in sV, P_inf in Pc — still resident) ========
  augA[i*65 + j] = Pc[ij33];
  augA[i*65 + 32 + j] = (i==j) ? 1.f : 0.f;
  lbar();
  gj_db<32>(augA, augB, 65, nullptr);   // Pc^{-1} in right half of augA
  { // T = Vc@A^T
    float acc = 0.f;
    #pragma unroll
    for (int k2 = 0; k2 < 32; ++k2) acc = fmaf(sV[i*33+k2], sA[j*33+k2], acc);
    sT[ij33] = acc;
  }
  lbar();
  { // J = T@Pinv
    float acc = 0.f;
    #pragma unroll
    for (int k2 = 0; k2 < 32; ++k2) acc = fmaf(sT[i*33+k2], augA[k2*65+32+j], acc);
    sJ[ij33] = acc;
  }
  lbar();
  wsp[PW_J + tid] = sJ[ij33];
  { // D = I - J@A
    float acc = (i==j) ? 1.f : 0.f;
    #pragma unroll
    for (int k2 = 0; k2 < 32; ++k2) acc = fmaf(-sJ[i*33+k2], sA[k2*33+j], acc);
    wsp[PW_D + tid] = acc;
  }
  sMs[ij33] = sJ[ij33];                 // Ms[0] = J
  { // T = J@Pc
    float acc = 0.f;
    #pragma unroll
    for (int k2 = 0; k2 < 32; ++k2) acc = fmaf(sJ[i*33+k2], Pc[k2*33+j], acc);
    sT[ij33] = acc;
  }
  lbar();
  { // X = B = Vc - T@J^T
    float acc = sV[ij33];
    #pragma unroll
    for (int k2 = 0; k2 < 32; ++k2) acc = fmaf(-sT[i*33+k2], sJ[j*33+k2], acc);
    sX[ij33] = acc;
  }
  lbar();
  // fused doubling: per level l: U = Ml@X ; X += U@Ml^T and Ms[l+1]=Ml@Ml
  for (int l = 0; l < 8; ++l) {
    const float* Ml = sMs + l*1056;
    { float acc = 0.f;
      #pragma unroll
      for (int k2 = 0; k2 < 32; ++k2) acc = fmaf(Ml[i*33+k2], sX[k2*33+j], acc);
      sU[ij33] = acc; }
    lbar();
    { float acc = sX[ij33];
      #pragma unroll
      for (int k2 = 0; k2 < 32; ++k2) acc = fmaf(sU[i*33+k2], Ml[j*33+k2], acc);
      sX[ij33] = acc; }
    if (l < 7) {
      float acc = 0.f;
      #pragma unroll
      for (int k2 = 0; k2 < 32; ++k2) acc = fmaf(Ml[i*33+k2], Ml[k2*33+j], acc);
      sMs[(l+1)*1056 + ij33] = acc;
    }
    lbar();
  }
  wsp[PW_VSINF + tid] = sX[ij33];          // Vs_inf
  // Xd doubling with Delta = Vc - Vs_inf (reuse Ms levels); sXd aliases augB
  float* sXd = augB;
  sXd[ij33] = sV[ij33] - sX[ij33];
  lbar();
  for (int l = 0; l < 8; ++l) {
    const float* Ml = sMs + l*1056;
    { float acc = 0.f;
      #pragma unroll
      for (int k2 = 0; k2 < 32; ++k2) acc = fmaf(Ml[i*33+k2], sXd[k2*33+j], acc);
      sU[ij33] = acc; }
    lbar();
    { float acc = sXd[ij33];
      #pragma unroll
      for (int k2 = 0; k2 < 32; ++k2) acc = fmaf(sU[i*33+k2], Ml[j*33+k2], acc);
      sXd[ij33] = acc; }
    lbar();
  }
  { // V12_inf = J@Vs_inf
    float acc = 0.f;
    #pragma unroll
    for (int k2 = 0; k2 < 32; ++k2) acc = fmaf(sJ[i*33+k2], sX[k2*33+j], acc);
    wsp[PW_V12INF + tid] = acc;
  }
  wsp[PW_SVSC + tid] = (float)(NTT - t_star)*sX[ij33] + sXd[ij33];
  sT[ij33] = (float)(NTT - 1 - t_star)*sX[ij33] + sXd[ij33];
  lbar();
  { float acc = 0.f;
    #pragma unroll
    for (int k2 = 0; k2 < 32; ++k2) acc = fmaf(sJ[i*33+k2], sT[k2*33+j], acc);
    wsp[PW_SV12C + tid] = acc;
  }
}

// ---- 64-lane split helpers (4/2-accumulator trees) ----
__device__ __forceinline__ float mvp16(const float* m, float v, int b0) {
  float s0=0.f, s1=0.f, s2=0.f, s3=0.f;
  #pragma unroll
  for (int q = 0; q < 4; ++q) {
    s0 = fmaf(m[q],    __shfl(v, b0+q),    s0);
    s1 = fmaf(m[4+q],  __shfl(v, b0+4+q),  s1);
    s2 = fmaf(m[8+q],  __shfl(v, b0+8+q),  s2);
    s3 = fmaf(m[12+q], __shfl(v, b0+12+q), s3);
  }
  return (s0+s1)+(s2+s3);
}
__device__ __forceinline__ float mvp8(const float* m, float v, int b0) {
  float s0=0.f, s1=0.f;
  #pragma unroll
  for (int q = 0; q < 4; ++q) {
    s0 = fmaf(m[q],   __shfl(v, b0+q),   s0);
    s1 = fmaf(m[4+q], __shfl(v, b0+4+q), s1);
  }
  return s0+s1;
}

// ==== guarded forward mean scan: muf_s = E muf_{s-1} + K x_s ====
__global__ __launch_bounds__(64) void k_muf(const float* __restrict__ x, float* __restrict__ out, float* __restrict__ wsp) {
  __shared__ float sx[16*321];
  const int lane = threadIdx.x;
  const int t_star = ((const int*)(wsp + PW_INTS))[0];
  const int sb = t_star + (int)blockIdx.x * CHL;
  if (sb >= NTT) return;
  const int len = (NTT - sb < CHL) ? (NTT - sb) : CHL;
  int gs = (blockIdx.x == 0) ? sb : sb - GRD;
  if (gs < 0) gs = 0;
  const int total = sb + len - gs;   // <= 320
  for (int q = 0; q < 16; ++q)
    for (int idx = lane; idx < total; idx += 64)
      sx[q*321 + idx] = x[(long)q*NTT + gs + idx];
  const int r = lane & 31, bm = (lane & 32) >> 1, bx = (lane & 32) >> 2;
  float e[16], kx[8];
  #pragma unroll
  for (int q = 0; q < 16; ++q) e[q] = wsp[PW_E + r*32 + bm + q];
  #pragma unroll
  for (int q = 0; q < 8; ++q) kx[q] = wsp[PW_K + r*16 + bx + q];
  float mf = (blockIdx.x == 0) ? wsp[PW_SMU + r] : 0.f;
  lbar();
  float* po = out + O_MUF + (long)r*NTT;
  for (int s = 0; s < total; ++s) {
    float xq = sx[(lane&15)*321 + s];
    float acc = mvp16(e, mf, bm) + mvp8(kx, xq, bx);
    acc += __shfl_xor(acc, 32);
    mf = acc;
    int tg = gs + s;
    if (tg >= sb && lane < 32) po[tg] = mf;
  }
}

// ==== merged parallel kernel: vs_tail | head_par | fill | mus-scan by blockIdx ====
__global__ __launch_bounds__(1024) void k_par1(
    const float* __restrict__ A, const float* __restrict__ Q,
    float* __restrict__ out, float* __restrict__ ws, float* __restrict__ wsp)
{
  __shared__ float sh[10400];
  const int tid = threadIdx.x;
  const int i = tid >> 5, j = tid & 31;
  const int ij33 = i*33 + j;
  const int b = blockIdx.x;
  const int t_star = ((const int*)(wsp + PW_INTS))[0];

  if (b < PB_HEAD) {
    // ---- vs_tail: Vs_{N-1-k} = Vs_inf + J^k Delta J^k^T ----
    const int k = b;
    float* sJ = sh; float* sM = sh+1056; float* sT = sh+2112; float* sDl = sh+3168; float* sVo = sh+4224;
    sJ[ij33] = wsp[PW_J + tid];
    sDl[ij33] = wsp[PW_VC + tid] - wsp[PW_VSINF + tid];
    const float vsi = wsp[PW_VSINF + tid];
    lbar();
    float vs;
    if (k == 0) {
      vs = vsi + sDl[ij33];
    } else {
      sM[ij33] = sJ[ij33];
      lbar();
      int hb = 31 - __builtin_clz((unsigned)k);
      for (int b2 = hb-1; b2 >= 0; --b2) {
        { float acc = 0.f;
          #pragma unroll
          for (int k2 = 0; k2 < 32; ++k2) acc = fmaf(sM[i*33+k2], sM[k2*33+j], acc);
          lbar(); sM[ij33] = acc; lbar(); }
        if ((k >> b2) & 1) {
          float acc = 0.f;
          #pragma unroll
          for (int k2 = 0; k2 < 32; ++k2) acc = fmaf(sM[i*33+k2], sJ[k2*33+j], acc);
          lbar(); sM[ij33] = acc; lbar();
        }
      }
      { float acc = 0.f;
        #pragma unroll
        for (int k2 = 0; k2 < 32; ++k2) acc = fmaf(sM[i*33+k2], sDl[k2*33+j], acc);
        sT[ij33] = acc; }
      lbar();
      { float acc = vsi;
        #pragma unroll
        for (int k2 = 0; k2 < 32; ++k2) acc = fmaf(sT[i*33+k2], sM[j*33+k2], acc);
        vs = acc; }
    }
    out[O_VS + (long)tid*NTT + (NTT-1-k)] = vs;
    sVo[ij33] = vs;
    lbar();
    if (k <= KTR-1) {
      float acc = 0.f;
      #pragma unroll
      for (int k2 = 0; k2 < 32; ++k2) acc = fmaf(sJ[i*33+k2], sVo[k2*33+j], acc);
      out[O_V12 + (long)tid*(NTT-1) + (NTT-2-k)] = acc;
    }
  } else if (b < PB_FILL) {
    // ---- head_par: per-t J_t, P_t ----
    const int tt = b - PB_HEAD;
    if (tt >= t_star) return;
    float* sA = sh; float* sQ2 = sh+1056; float* sVf = sh+2112; float* sAV = sh+3168; float* sP = sh+4224;
    float* aug = sh+5280; float* aug2 = sh+7360;
    sA[ij33] = A[tid]; sQ2[ij33] = Q[tid];
    sVf[ij33] = out[O_VF + (long)tid*NTT + tt];
    lbar();
    { float acc = 0.f;
      #pragma unroll
      for (int k2 = 0; k2 < 32; ++k2) acc = fmaf(sA[i*33+k2], sVf[k2*33+j], acc);
      sAV[ij33] = acc;
    }
    lbar();
    { float a1 = sQ2[ij33];
      float a2 = sQ2[j*33+i];
      #pragma unroll
      for (int k2 = 0; k2 < 32; ++k2) {
        a1 = fmaf(sAV[i*33+k2], sA[j*33+k2], a1);
        a2 = fmaf(sAV[j*33+k2], sA[i*33+k2], a2);
      }
      float ps = 0.5f*(a1 + a2);
      sP[ij33] = ps;
      aug[i*65+j] = ps; aug[i*65+32+j] = (i==j) ? 1.f : 0.f;
    }
    lbar();
    gj_db<32>(aug, aug2, 65, nullptr);
    { float acc = 0.f;
      #pragma unroll
      for (int k2 = 0; k2 < 32; ++k2) acc = fmaf(sVf[i*33+k2], sA[j*33+k2], acc);
      sAV[ij33] = acc;
    }
    lbar();
    { float acc = 0.f;
      #pragma unroll
      for (int k2 = 0; k2 < 32; ++k2) acc = fmaf(sAV[i*33+k2], aug[k2*65+32+j], acc);
      ws[WS_JT + (long)tt*1024 + tid] = acc;
    }
    ws[WS_PT + (long)tt*1024 + tid] = sP[ij33];
  } else if (b < PB_MUS) {
    // ---- fill: (row, chunk) pair, vectorized float4 stores ----
    const int e = b - PB_FILL;
    const int ij = e >> 2;
    const int c  = e & 3;
    const int clo = c*4096, chi = clo + 4096;
    const int tb = NTT - 1 - KTR;
    int lo = (t_star > clo) ? t_star : clo;
    int hiV = (NTT < chi) ? NTT : chi;
    int hiS = (tb < chi) ? tb : chi;
    const float vf = wsp[PW_VC + ij];
    const float vs = wsp[PW_VSINF + ij];
    const float v12 = wsp[PW_V12INF + ij];
    fill4(out + O_VF + (long)ij*NTT, lo, hiV, vf, tid);
    fill4(out + O_VS + (long)ij*NTT, lo, hiS, vs, tid);
    fill4(out + O_V12 + (long)ij*(NTT-1), lo, hiS, v12, tid);
  } else {
    // ---- guarded backward mean scan: mus_t = D muf_t + J mus_{t+1} ----
    const int c = b - PB_MUS;
    const int te = (NTT-1) - c*CHL;
    if (te <= t_star) return;
    const int ts = (te - CHL > t_star) ? (te - CHL) : t_star;
    int start = te + GRD;
    if (start > NTT-1) start = NTT-1;
    const int total = start - ts + 1;   // <= 321
    float* smf = sh;                    // 32 x 321
    for (int e = tid; e < 32*total; e += 1024) {
      int q = e / total, idx = e - q*total;
      smf[q*321 + idx] = out[O_MUF + (long)q*NTT + ts + idx];
    }
    lbar();
    if (tid >= 64) return;
    const int lane = tid;
    const int r = lane & 31, bm = (lane & 32) >> 1;
    float dd[16], jj[16];
    #pragma unroll
    for (int q = 0; q < 16; ++q) { dd[q] = wsp[PW_D + r*32 + bm + q]; jj[q] = wsp[PW_J + r*32 + bm + q]; }
    float m;
    if (start == NTT-1) {
      m = smf[r*321 + (total-1)];       // mus_{N-1} = muf_{N-1} exact
      if (c == 0 && lane < 32) out[O_MUS + (long)r*NTT + (NTT-1)] = m;
    } else {
      m = 0.f;                          // guard: decays by rho^GRD before te
    }
    for (int tt = start-1; tt >= ts; --tt) {
      float mv = smf[r*321 + (tt - ts)];
      float acc = mvp16(dd, mv, bm) + mvp16(jj, m, bm);
      acc += __shfl_xor(acc, 32);
      m = acc;
      if (tt < te && lane < 32) out[O_MUS + (long)r*NTT + tt] = m;
    }
  }
}

// ======== head: serial recursion, 2 barrier rounds per step ========
__global__ __launch_bounds__(1024) void k_head_ser(
    const float* __restrict__ A, float* __restrict__ out,
    float* __restrict__ ws, float* __restrict__ wsp)
{
  __shared__ float sA[32*33], sJa[32*33], sJb[32*33], sT1[32*33], sT2[32*33], sVs[32*33];
  __shared__ float smufT[32], sam[32], smsp[32];
  const int tid = threadIdx.x;
  const int i = tid >> 5, j = tid & 31;
  const int ij33 = i*33 + j;
  const int t_star = ((const int*)(wsp + PW_INTS))[0];
  sA[ij33] = A[tid];
  float hsvs = 0.f, hsv12 = 0.f;
  if (t_star > 0) {
    float vsinf = wsp[PW_VSINF + tid];
    int tt = t_star - 1;
    float jc = ws[WS_JT + (long)tt*1024 + tid];
    float pc = ws[WS_PT + (long)tt*1024 + tid];
    float vfc = out[O_VF + (long)tid*NTT + tt];
    float mufc = (tid < 32) ? out[O_MUF + (long)tid*NTT + tt] : 0.f;
    if (tid < 32) smsp[tid] = out[O_MUS + (long)tid*NTT + t_star];
    sVs[ij33] = vsinf;
    sJa[ij33] = jc;
    sT1[ij33] = vsinf - pc;
    if (tid < 32) smufT[tid] = mufc;
    lbar();
    float* Jc = sJa; float* Jn = sJb;
    for (; tt >= 0; --tt) {
      float jN = 0.f, pN = 0.f, vfN = 0.f, mufN = 0.f;
      if (tt > 0) {
        jN = ws[WS_JT + (long)(tt-1)*1024 + tid];
        pN = ws[WS_PT + (long)(tt-1)*1024 + tid];
        vfN = out[O_VF + (long)tid*NTT + (tt-1)];
        if (tid < 32) mufN = out[O_MUF + (long)tid*NTT + (tt-1)];
      }
      {
        float t2 = 0.f, v12 = 0.f;
        #pragma unroll
        for (int k2 = 0; k2 < 32; ++k2) {
          t2  = fmaf(Jc[i*33+k2], sT1[k2*33+j], t2);
          v12 = fmaf(Jc[i*33+k2], sVs[k2*33+j], v12);
        }
        sT2[ij33] = t2;
        out[O_V12 + (long)tid*(NTT-1) + tt] = v12;
        hsv12 += v12;
      }
      if (tid < 32) {
        float a = 0.f;
        #pragma unroll
        for (int k2 = 0; k2 < 32; ++k2) a = fmaf(sA[tid*33+k2], smufT[k2], a);
        sam[tid] = a;
      }
      lbar();
      {
        float vsn = vfc;
        #pragma unroll
        for (int k2 = 0; k2 < 32; ++k2) vsn = fmaf(sT2[i*33+k2], Jc[j*33+k2], vsn);
        out[O_VS + (long)tid*NTT + tt] = vsn;
        hsvs += vsn;
        sVs[ij33] = vsn;
        sT1[ij33] = vsn - pN;
        Jn[ij33] = jN;
      }
      if (tid < 32) {
        float mv = smufT[tid];
        #pragma unroll
        for (int k2 = 0; k2 < 32; ++k2) mv = fmaf(Jc[tid*33+k2], smsp[k2] - sam[k2], mv);
        out[O_MUS + (long)tid*NTT + tt] = mv;
        smsp[tid] = mv;
        smufT[tid] = mufN;
      }
      vfc = vfN;
      { float* sw = Jc; Jc = Jn; Jn = sw; }
      lbar();
    }
  }
  wsp[PW_HSVS + tid] = hsvs;
  wsp[PW_HSV12 + tid] = hsv12;
}

// gram partials: Gall, G12, Gx, xx per t-chunk
__global__ __launch_bounds__(256) void k_gram(const float* __restrict__ out, const float* __restrict__ x, float* __restrict__ ws) {
  __shared__ float smu[32][257];
  __shared__ float sx[256][16];
  const int b = blockIdx.x;
  const int t0 = b*256;
  for (int e = threadIdx.x; e < 32*257; e += 256) {
    int i2 = e/257, tt = e - i2*257;
    int t = t0 + tt;
    smu[i2][tt] = (t < NTT) ? out[O_MUS + (long)i2*NTT + t] : 0.f;
  }
  for (int e = threadIdx.x; e < 16*256; e += 256) {
    int j2 = e >> 8, tt = e & 255;
    sx[tt][j2] = x[(long)j2*NTT + t0 + tt];
  }
  __syncthreads();
  float* pb = ws + WS_GRAM + (long)b*GRAM_STRIDE;
  const int lim12 = (t0 + 256 <= NTT-1) ? 256 : (NTT-1-t0);
  for (int k = 0; k < 4; ++k) {
    int ij = threadIdx.x + k*256; int i2 = ij>>5, j2 = ij&31;
    float g = 0.f, g12 = 0.f;
    for (int tt = 0; tt < 256; ++tt) g = fmaf(smu[i2][tt], smu[j2][tt], g);
    for (int tt = 0; tt < lim12; ++tt) g12 = fmaf(smu[i2][tt], smu[j2][tt+1], g12);
    pb[ij] = g; pb[1024+ij] = g12;
  }
  for (int k = 0; k < 2; ++k) {
    int ij = threadIdx.x + k*256; int i2 = ij>>4, j2 = ij&15;
    float g = 0.f;
    for (int tt = 0; tt < 256; ++tt) g = fmaf(smu[i2][tt], sx[tt][j2], g);
    pb[2048+ij] = g;
  }
  {
    int ij = threadIdx.x; int i2 = ij>>4, j2 = ij&15;
    float g = 0.f;
    for (int tt = 0; tt < 256; ++tt) g = fmaf(sx[tt][i2], sx[tt][j2], g);
    pb[2560+ij] = g;
  }
}

// EM statistics + log-likelihood (fused GJ passes)
__global__ __launch_bounds__(1024) void k_final(float* __restrict__ out, float* __restrict__ ws) {
  __shared__ float s_zz[1056], s_z11[1056], s_z12[1056], s_z22[1056];
  __shared__ float s_An[1056], s_T[1056], s_Qz[1056], s_W[1056];
  __shared__ float s_Gx[544], s_xx[272], s_Cn[528], s_U16[528], s_T16[272], s_Qx[272];
  __shared__ float a3[3*2080], b3[3*2080];
  __shared__ float qxa[528], qxb[528];
  __shared__ float s_mu0[32], s_muN[32];
  __shared__ float s_ld[3];
  __shared__ double s_red[16];
  const int tid = threadIdx.x;
  const int i = tid>>5, j = tid&31;
  const int ij33 = i*33+j;
  double ell_acc = 0.0;
  const double L2PI = 1.8378770664093454836;
  const float* wsp = ws + WS_PAR;

  float gall = 0.f, g12 = 0.f;
  for (int b = 0; b < 64; ++b) {
    gall += ws[WS_GRAM + (long)b*GRAM_STRIDE + tid];
    g12  += ws[WS_GRAM + (long)b*GRAM_STRIDE + 1024 + tid];
  }
  float svs  = wsp[PW_HSVS + tid] + wsp[PW_SVSC + tid];
  float sv12 = wsp[PW_HSV12 + tid] + wsp[PW_SV12C + tid];
  float vs0  = out[O_VS + (long)tid*NTT + 0];
  float vsN  = out[O_VS + (long)tid*NTT + (NTT-1)];
  if (tid < 512) { float g = 0.f; for (int b = 0; b < 64; ++b) g += ws[WS_GRAM + (long)b*GRAM_STRIDE + 2048 + tid]; s_Gx[(tid>>4)*17 + (tid&15)] = g; }
  if (tid < 256) { float g = 0.f; for (int b = 0; b < 64; ++b) g += ws[WS_GRAM + (long)b*GRAM_STRIDE + 2560 + tid]; s_xx[(tid>>4)*17 + (tid&15)] = g; }
  if (tid < 32) { s_mu0[tid] = out[O_MUS + (long)tid*NTT + 0]; s_muN[tid] = out[O_MUS + (long)tid*NTT + (NTT-1)]; }
  if (tid < 3) s_ld[tid] = 0.f;
  lbar();
  s_zz[ij33]  = gall + svs;
  s_z11[ij33] = (gall - s_muN[i]*s_muN[j]) + (svs - vsN);
  s_z22[ij33] = (gall - s_mu0[i]*s_mu0[j]) + (svs - vs0);
  s_z12[ij33] = g12 + sv12;
  s_W[ij33]   = vs0;
  lbar();

  {
    float p0n = 0.5f*(s_W[i*33+j] + s_W[j*33+i]);
    float a_  = s_mu0[i]*s_mu0[j];
    float aT  = s_mu0[j]*s_mu0[i];
    float u0  = ((a_ + s_W[ij33]) - (a_ + aT)) + a_;
    s_T[ij33] = u0;
    a3[i*65+j] = p0n;             a3[i*65+32+j] = (i==j) ? 1.f : 0.f;
    a3[2080 + i*65+j] = s_z11[ij33]; a3[2080 + i*65+32+j] = (i==j) ? 1.f : 0.f;
    a3[4160 + i*65+j] = s_zz[ij33];  a3[4160 + i*65+32+j] = (i==j) ? 1.f : 0.f;
  }
  lbar();
  { float q0 = 0.5f*(s_T[i*33+j] + s_T[j*33+i]); s_Qz[ij33] = q0; }
  lbar();
  gj3_db(a3, b3, &s_ld[0]);
  {
    double p = (double)a3[i*65+32+j] * (double)s_Qz[j*33+i];
    double tr = block_sum_d(p, s_red);
    if (tid == 0) ell_acc += -0.5*(32.0*L2PI + (double)s_ld[0]) - 0.5*tr;
  }

  {
    float acc = 0.f;
    #pragma unroll
    for (int k2 = 0; k2 < 32; ++k2) acc = fmaf(s_z12[k2*33+i], a3[2080 + k2*65+32+j], acc);
    s_An[ij33] = acc;
  }
  if (tid < 512) {
    int i16 = tid>>5, j32 = tid&31;
    float acc = 0.f;
    #pragma unroll
    for (int k2 = 0; k2 < 32; ++k2) acc = fmaf(s_Gx[k2*17+i16], a3[4160 + k2*65+32+j32], acc);
    s_Cn[i16*33+j32] = acc;
  }
  lbar();
  {
    float acc = 0.f;
    #pragma unroll
    for (int k2 = 0; k2 < 32; ++k2) acc = fmaf(s_An[i*33+k2], s_z12[k2*33+j], acc);
    s_T[ij33] = acc;
  }
  {
    float acc = 0.f;
    #pragma unroll
    for (int k2 = 0; k2 < 32; ++k2) acc = fmaf(s_An[i*33+k2], s_z11[k2*33+j], acc);
    s_W[ij33] = acc;
  }
  if (tid < 256) {
    int a2 = tid>>4, b2 = tid&15;
    float acc = 0.f;
    #pragma unroll
    for (int k2 = 0; k2 < 32; ++k2) acc = fmaf(s_Cn[a2*33+k2], s_Gx[k2*17+b2], acc);
    s_T16[a2*17+b2] = acc;
  }
  if (tid >= 512) {
    int tt2 = tid - 512;
    int i16 = tt2>>5, j32 = tt2&31;
    float acc = 0.f;
    #pragma unroll
    for (int k2 = 0; k2 < 32; ++k2) acc = fmaf(s_Cn[i16*33+k2], s_zz[k2*33+j32], acc);
    s_U16[i16*33+j32] = acc;
  }
  lbar();
  {
    float azza = 0.f;
    #pragma unroll
    for (int k2 = 0; k2 < 32; ++k2) azza = fmaf(s_W[i*33+k2], s_An[j*33+k2], azza);
    float u = (s_z22[ij33] - (s_T[i*33+j]+s_T[j*33+i])) + azza;
    s_Qz[ij33] = u;
  }
  if (tid < 256) {
    int a2 = tid>>4, b2 = tid&15;
    float czzc = 0.f;
    #pragma unroll
    for (int k2 = 0; k2 < 32; ++k2) czzc = fmaf(s_U16[a2*33+k2], s_Cn[b2*33+k2], czzc);
    float u = (s_xx[a2*17+b2] - (s_T16[a2*17+b2]+s_T16[b2*17+a2])) + czzc;
    s_Qx[a2*17+b2] = u;
  }
  lbar();
  {
    float qz = 0.5f*(s_Qz[i*33+j]+s_Qz[j*33+i]);
    s_T[ij33] = qz;
    a3[i*65+j] = qz/16383.0f; a3[i*65+32+j] = (i==j) ? 1.f : 0.f;
  }
  if (tid < 256) {
    int a2 = tid>>4, b2 = tid&15;
    float qx = 0.5f*(s_Qx[a2*17+b2]+s_Qx[b2*17+a2]);
    s_T16[a2*17+b2] = qx;
    qxa[a2*33+b2] = qx/16384.0f; qxa[a2*33+16+b2] = (a2==b2) ? 1.f : 0.f;
  }
  lbar();
  gjzx_db(a3, b3, qxa, qxb, &s_ld[1], &s_ld[2]);
  {
    double p = (double)a3[i*65+32+j] * (double)s_T[j*33+i];
    double tr = block_sum_d(p, s_red);
    if (tid == 0) ell_acc += -8191.5*(32.0*L2PI + (double)s_ld[1]) - 0.5*tr;
  }
  {
    double p = (i < 16 && j < 16) ? (double)qxa[i*33+16+j] * (double)s_T16[j*17+i] : 0.0;
    double tr = block_sum_d(p, s_red);
    if (tid == 0) {
      ell_acc += -8192.0*(16.0*L2PI + (double)s_ld[2]) - 0.5*tr;
      out[0] = (float)ell_acc;
    }
  }
}

extern "C" void kernel_launch(void* const* d_in, const int* in_sizes, int n_in,
                              void* d_out, int out_size, void* d_ws, size_t ws_size,
                              hipStream_t stream) {
  (void)in_sizes; (void)n_in; (void)out_size; (void)ws_size;
  const float* x  = (const float*)d_in[0];
  const float* A  = (const float*)d_in[1];
  const float* C  = (const float*)d_in[2];
  const float* Q  = (const float*)d_in[3];
  const float* R  = (const float*)d_in[4];
  const float* m0 = (const float*)d_in[5];
  const float* P0 = (const float*)d_in[6];
  float* out = (float*)d_out;
  float* ws  = (float*)d_ws;
  float* wsp = ws + WS_PAR;

  hipLaunchKernelGGL(k_fwd, dim3(1), dim3(1024), 0, stream, A, C, Q, R, m0, P0, x, out, wsp);
  hipLaunchKernelGGL(k_muf, dim3(NCH), dim3(64), 0, stream, x, out, wsp);
  hipLaunchKernelGGL(k_par1, dim3(PB_END), dim3(1024), 0, stream, A, Q, out, ws, wsp);
  hipLaunchKernelGGL(k_head_ser, dim3(1), dim3(1024), 0, stream, A, out, ws, wsp);
  hipLaunchKernelGGL(k_gram, dim3(64), dim3(256), 0, stream, out, x, ws);
  hipLaunchKernelGGL(k_final, dim3(1), dim3(1024), 0, stream, out, ws);
}